// Round 4
// baseline (384.180 us; speedup 1.0000x reference)
//
#include <hip/hip_runtime.h>

typedef unsigned short u16;
typedef unsigned int u32;

typedef __bf16 bf16x8 __attribute__((ext_vector_type(8)));
typedef unsigned short ushort8 __attribute__((ext_vector_type(8)));
typedef float f32x16 __attribute__((ext_vector_type(16)));

// workspace offsets (in floats)
#define STATSP 2048     // 16*12*64*2 = 24576 floats of stats partials
#define EPOFF 32768     // 3*96*256 = 73728 u32: packed (hi|lo<<16) bf16 of E[s][t][o]
#define KKOFF0 591872
#define KKOFF1 616448
#define KKOFF2 665600
#define WOFF 763904
#define R0OFF 5482496
#define R1OFF 6072320
#define R2OFF 7251968
#define HTOTOFF 11675648
// total = 11712512 floats = ~46.9 MB
// fp64 chain scratch lives INSIDE the Wtil region [WOFF, R0OFF); it is fully
// consumed before k_s3 overwrites Wtil. Offsets in doubles relative to
// (double*)(ws + WOFF):
#define AD64 0        // 3*65536 doubles  (Ad fp64, per scale)
#define PD64 196608   // 6*65536 doubles  (P ping-pong, per scale)
#define KKD64 589824  // 672*256 doubles  (KK rows: s0 96, s1 192, s2 384)
// KK (packed hi/lo u32) lives at KKOFF* ; Wtil2 (packed u32, layout
// [i>>3][n][i&7], n = x*96+t) lives at WOFF + jidx*786432 (u32 view).

// float -> packed u32: low16 = bf16 RNE of a, high16 = bf16 (trunc) of residual
__device__ __forceinline__ u32 pack_hl(float a) {
  u32 bits = __builtin_bit_cast(u32, a);
  u32 hi = (bits + 0x7fffu + ((bits >> 16) & 1u)) >> 16;
  float hif = __builtin_bit_cast(float, hi << 16);
  float r = a - hif;
  u32 lo = __builtin_bit_cast(u32, r) >> 16;
  return hi | (lo << 16);
}

__device__ __forceinline__ void unpk8(const u32* p, bf16x8& h, bf16x8& l) {
  ushort8 hu, lu;
#pragma unroll
  for (int j = 0; j < 8; ++j) {
    u32 v = p[j];
    hu[j] = (unsigned short)(v & 0xffffu);
    lu[j] = (unsigned short)(v >> 16);
  }
  h = __builtin_bit_cast(bf16x8, hu);
  l = __builtin_bit_cast(bf16x8, lu);
}

// ---- k_pre: A->fp64, seed KK row0, stats1, zero Htot, pack E hi/lo ----
__global__ __launch_bounds__(256) void k_pre(const float* __restrict__ Ab,
                                             const float* __restrict__ Bb,
                                             const float* __restrict__ xin,
                                             const float* __restrict__ ev,
                                             float* __restrict__ ws) {
  __shared__ float rs[4][64], rq[4][64];
  int blk = blockIdx.x, tid = threadIdx.x;
  if (blk < 771) {
    double* dws = (double*)(ws + WOFF);
    int idx = blk * 256 + tid;
    if (idx < 196608) {
      dws[AD64 + idx] = (double)Ab[idx];
    } else {
      int g = idx - 196608;  // 0..767 (grid sized exactly)
      const int rowoff[3] = {0, 24576, 73728};
      const int kko[3] = {KKOFF0, KKOFF1, KKOFF2};
      int s = g >> 8, i = g & 255;
      float v = Bb[g];
      dws[KKD64 + rowoff[s] + i] = (double)v;
      ((u32*)ws)[kko[s] + i] = pack_hl(v);
    }
  } else if (blk < 963) {
    int b2 = blk - 771;  // 0..191
    int b = b2 / 12, part = b2 % 12;
    int j = tid & 63, g = tid >> 6;
    const float* xp = xin + ((size_t)b * 720 + part * 60 + g) * 64 + j;
    float sum = 0.f, ss = 0.f;
#pragma unroll
    for (int i = 0; i < 15; ++i) {
      float v = xp[(size_t)i * 256];
      sum += v; ss += v * v;
    }
    rs[g][j] = sum; rq[g][j] = ss;
    __syncthreads();
    if (g == 0) {
      float s = rs[0][j] + rs[1][j] + rs[2][j] + rs[3][j];
      float q = rq[0][j] + rq[1][j] + rq[2][j] + rq[3][j];
      float* dst = ws + STATSP + ((size_t)b2 * 64 + j) * 2;
      dst[0] = s; dst[1] = q;
    }
  } else if (blk < 987) {
    int idx = (blk - 963) * 256 + tid;
    for (; idx < 36864; idx += 24 * 256) ws[HTOTOFF + idx] = 0.f;
  } else {
    // E pack: ev layout [3][96][256] linear -> packed u32 table
    int idx = (blk - 987) * 256 + tid;  // 0..73727 (288 blocks exactly)
    ((u32*)ws)[EPOFF + idx] = pack_hl(ev[idx]);
  }
}

// ---- fp64 chain GEMM, 32x32 tiles, 2x2 micro, K=N=256, register prefetch ----
struct G64Jobs {
  const double* A[8]; const double* B[8]; double* C[8]; float* CF[8];
  int M[8]; int transB[8]; int tile0[8];
  int njobs;
};

__global__ __launch_bounds__(256) void k_gemm64(G64Jobs jb) {
  int bid = blockIdx.x;
  int j = 0;
  for (int q = 1; q < jb.njobs; ++q) if (bid >= jb.tile0[q]) j = q;
  int local = bid - jb.tile0[j];
  int tm = local >> 3, tn = local & 7;
  const double* A = jb.A[j];
  const double* Bm = jb.B[j];
  double* C = jb.C[j];
  float* CF = jb.CF[j];
  int M = jb.M[j], tB = jb.transB[j];
  int row0 = tm * 32, col0 = tn * 32;
  __shared__ double As[32][33], Bs[32][33];
  int tid = threadIdx.x;
  int ty = tid >> 4, tx = tid & 15;
  int lr = tid >> 3, lk = (tid & 7) << 2;
  double va[4], vb[4];
#pragma unroll
  for (int u = 0; u < 4; ++u) {
    va[u] = (row0 + lr < M) ? A[(size_t)(row0 + lr) * 256 + lk + u] : 0.0;
    vb[u] = tB ? Bm[(size_t)(col0 + lr) * 256 + lk + u]
               : Bm[(size_t)lr * 256 + col0 + lk + u];
  }
  double a00 = 0., a01 = 0., a10 = 0., a11 = 0.;
  for (int kc = 0; kc < 256; kc += 32) {
#pragma unroll
    for (int u = 0; u < 4; ++u) {
      As[lr][lk + u] = va[u];
      if (tB) Bs[lk + u][lr] = vb[u];
      else    Bs[lr][lk + u] = vb[u];
    }
    __syncthreads();
    if (kc < 224) {
      int kn = kc + 32;
#pragma unroll
      for (int u = 0; u < 4; ++u) {
        va[u] = (row0 + lr < M) ? A[(size_t)(row0 + lr) * 256 + kn + lk + u] : 0.0;
        vb[u] = tB ? Bm[(size_t)(col0 + lr) * 256 + kn + lk + u]
                   : Bm[(size_t)(kn + lr) * 256 + col0 + lk + u];
      }
    }
#pragma unroll 8
    for (int k = 0; k < 32; ++k) {
      double x0 = As[2 * ty][k], x1 = As[2 * ty + 1][k];
      double y0 = Bs[k][2 * tx], y1 = Bs[k][2 * tx + 1];
      a00 = fma(x0, y0, a00); a01 = fma(x0, y1, a01);
      a10 = fma(x1, y0, a10); a11 = fma(x1, y1, a11);
    }
    __syncthreads();
  }
  int r0 = row0 + 2 * ty, c0 = col0 + 2 * tx;
  if (r0 < M) {
    C[(size_t)r0 * 256 + c0] = a00; C[(size_t)r0 * 256 + c0 + 1] = a01;
    if (CF) {
      ((u32*)CF)[(size_t)r0 * 256 + c0] = pack_hl((float)a00);
      ((u32*)CF)[(size_t)r0 * 256 + c0 + 1] = pack_hl((float)a01);
    }
  }
  if (r0 + 1 < M) {
    C[(size_t)(r0 + 1) * 256 + c0] = a10; C[(size_t)(r0 + 1) * 256 + c0 + 1] = a11;
    if (CF) {
      ((u32*)CF)[(size_t)(r0 + 1) * 256 + c0] = pack_hl((float)a10);
      ((u32*)CF)[(size_t)(r0 + 1) * 256 + c0 + 1] = pack_hl((float)a11);
    }
  }
}

// ---- S3 (MFMA split-bf16, 6 waves, 16-VGPR acc): Wtil = w x E^T ----
// R3 failed from register starvation: acc[3]x16 = 48 of 56 VGPRs -> compiler
// serialized every load behind vmcnt(0). Now wave = (il, f): one i-row, ONE
// 32-t fragment, full K=256 -> acc is a single f32x16 (16 VGPRs). Explicit
// register double-buffer prefetches next k-step's 8 A-floats + 8 B-u32 under
// the current 3 MFMAs. A-fragments re-read by 3 waves are L1-resident.
// LDS only pairs (il=0,il=1) for the uint2 store. 1 barrier total.
// Output PACKED (hi|lo u32), layout Wtil2[i>>3][n][i&7], n=x*96+t.
__global__ __launch_bounds__(384) void k_s3(const float* __restrict__ wr,
                                            const float* __restrict__ wi,
                                            float* __restrict__ ws) {
  __shared__ u32 ls[3168];  // [3 f][32 x][33] pairing scratch (12.7 KB)
  int bid = blockIdx.x;
  int jidx = bid >> 7;
  int r127 = bid & 127;
  int mb = ((r127 & 7) << 4) | (r127 >> 3);  // XCD-group swizzle (bijective)
  int s = jidx >> 1, p = jidx & 1;
  const float* w = (p ? wi : wr) + (size_t)s * 2097152;
  const u32* ep = (const u32*)ws + EPOFF + s * 24576;
  int i0 = mb * 2;
  int tid = threadIdx.x;
  int lane = tid & 63;
  int wid = tid >> 6;
  int il = wid & 1, f = wid >> 1;

  int tcol = lane & 31;          // A row (x) / B col (t within f) / D col
  int og8 = (lane >> 5) << 3;    // k sub-group (which 8 of 16 k)
  const float* aw0 = w + (((size_t)(i0 + il) * 256 + og8) << 5) + tcol;
  const u32* bsrc = ep + (size_t)(f * 32 + tcol) * 256 + og8;

  f32x16 acc;
#pragma unroll
  for (int r = 0; r < 16; ++r) acc[r] = 0.f;

  float fa[8]; uint4 vb0, vb1;
#pragma unroll
  for (int j = 0; j < 8; ++j) fa[j] = aw0[(size_t)j << 5];
  vb0 = *(const uint4*)(bsrc);
  vb1 = *(const uint4*)(bsrc + 4);

#pragma unroll
  for (int ks = 0; ks < 16; ++ks) {
    float fan[8]; uint4 nb0, nb1;
    if (ks < 15) {  // issue next-step loads BEFORE consuming current
      const float* awn = aw0 + ((size_t)(ks + 1) << 9);
#pragma unroll
      for (int j = 0; j < 8; ++j) fan[j] = awn[(size_t)j << 5];
      nb0 = *(const uint4*)(bsrc + (ks + 1) * 16);
      nb1 = *(const uint4*)(bsrc + (ks + 1) * 16 + 4);
    }
    u32 ap[8];
#pragma unroll
    for (int j = 0; j < 8; ++j) ap[j] = pack_hl(fa[j]);
    bf16x8 ah, al;
    unpk8(ap, ah, al);
    u32 bp[8] = {vb0.x, vb0.y, vb0.z, vb0.w, vb1.x, vb1.y, vb1.z, vb1.w};
    bf16x8 bh, bl;
    unpk8(bp, bh, bl);
    acc = __builtin_amdgcn_mfma_f32_32x32x16_bf16(ah, bh, acc, 0, 0, 0);
    acc = __builtin_amdgcn_mfma_f32_32x32x16_bf16(ah, bl, acc, 0, 0, 0);
    acc = __builtin_amdgcn_mfma_f32_32x32x16_bf16(al, bh, acc, 0, 0, 0);
    if (ks < 15) {
#pragma unroll
      for (int j = 0; j < 8; ++j) fa[j] = fan[j];
      vb0 = nb0; vb1 = nb1;
    }
  }

  // pack own values; pair il=0/il=1 through LDS; il=1 stores uint2
  int x0 = (lane >> 5) << 2;
  u32 mine[16];
#pragma unroll
  for (int r = 0; r < 16; ++r) mine[r] = pack_hl(acc[r]);
  if (il == 0) {
#pragma unroll
    for (int r = 0; r < 16; ++r) {
      int row = x0 + (r & 3) + ((r >> 2) << 3);
      ls[f * 1056 + row * 33 + tcol] = mine[r];
    }
  }
  __syncthreads();
  if (il == 1) {
    u32* W2 = (u32*)(ws + WOFF) + (size_t)jidx * 786432 +
              (size_t)(mb >> 2) * 24576 + ((mb & 3) << 1);
#pragma unroll
    for (int r = 0; r < 16; ++r) {
      int row = x0 + (r & 3) + ((r >> 2) << 3);
      uint2 st;
      st.x = ls[f * 1056 + row * 33 + tcol];
      st.y = mine[r];
      *(uint2*)(W2 + (size_t)(row * 96 + f * 32 + tcol) * 8) = st;
    }
  }
}

// ---- S4 (MFMA split-bf16, zero-LDS): R[d,n] = sum_i KK[d,i]*Wtil[i,n] ----
// A = packed KK [T][256] (k-contiguous), B = Wtil2 [i>>3][n][i&7]
// (k-contiguous within each 8-group). Both fragments are direct 32B global
// reads (L2-resident). Block = 32 d x 256 n, 4 waves (one 64-n slice each).
__global__ __launch_bounds__(256) void k_s4(float* __restrict__ ws) {
  int bid = blockIdx.x;
  const int cums[6] = {0, 36, 72, 144, 216, 360};  // tiles: (T/32)*12 per (s,p)
  int jidx = 0;
#pragma unroll
  for (int q = 1; q < 6; ++q) if (bid >= cums[q]) jidx = q;
  int local = bid - cums[jidx];
  int s = jidx >> 1, p = jidx & 1;
  const int Ts[3] = {96, 192, 384};
  const int KKo[3] = {KKOFF0, KKOFF1, KKOFF2};
  const int Ro[3] = {R0OFF, R1OFF, R2OFF};
  int T = Ts[s];
  int td = local / 12, tn = local % 12;
  int d0 = td * 32;
  int tid = threadIdx.x;
  int lane = tid & 63, wid = tid >> 6;
  int n0 = tn * 256 + wid * 64;
  int l31 = lane & 31, kg = lane >> 5;
  const u32* Ap = (const u32*)ws + KKo[s] + (size_t)(d0 + l31) * 256 + kg * 8;
  const u32* Bp = (const u32*)ws + WOFF + (size_t)jidx * 786432 + (size_t)kg * 24576;
  const u32* b0p = Bp + (size_t)(n0 + l31) * 8;
  const u32* b1p = Bp + (size_t)(n0 + 32 + l31) * 8;
  float* C = ws + Ro[s] + (size_t)p * T * 3072;

  f32x16 acc0, acc1;
#pragma unroll
  for (int r = 0; r < 16; ++r) { acc0[r] = 0.f; acc1[r] = 0.f; }

#pragma unroll 2
  for (int ks = 0; ks < 16; ++ks) {
    uint4 a0 = *(const uint4*)(Ap + ks * 16);
    uint4 a1 = *(const uint4*)(Ap + ks * 16 + 4);
    size_t bo = (size_t)ks * 49152;  // 2 groups of 8 i per kstep
    uint4 x0 = *(const uint4*)(b0p + bo);
    uint4 x1 = *(const uint4*)(b0p + bo + 4);
    uint4 y0 = *(const uint4*)(b1p + bo);
    uint4 y1 = *(const uint4*)(b1p + bo + 4);
    u32 ap[8] = {a0.x, a0.y, a0.z, a0.w, a1.x, a1.y, a1.z, a1.w};
    bf16x8 ah, al;
    unpk8(ap, ah, al);
    {
      u32 bp[8] = {x0.x, x0.y, x0.z, x0.w, x1.x, x1.y, x1.z, x1.w};
      bf16x8 bh, bl;
      unpk8(bp, bh, bl);
      acc0 = __builtin_amdgcn_mfma_f32_32x32x16_bf16(ah, bh, acc0, 0, 0, 0);
      acc0 = __builtin_amdgcn_mfma_f32_32x32x16_bf16(ah, bl, acc0, 0, 0, 0);
      acc0 = __builtin_amdgcn_mfma_f32_32x32x16_bf16(al, bh, acc0, 0, 0, 0);
      acc0 = __builtin_amdgcn_mfma_f32_32x32x16_bf16(al, bl, acc0, 0, 0, 0);
    }
    {
      u32 bp[8] = {y0.x, y0.y, y0.z, y0.w, y1.x, y1.y, y1.z, y1.w};
      bf16x8 bh, bl;
      unpk8(bp, bh, bl);
      acc1 = __builtin_amdgcn_mfma_f32_32x32x16_bf16(ah, bh, acc1, 0, 0, 0);
      acc1 = __builtin_amdgcn_mfma_f32_32x32x16_bf16(ah, bl, acc1, 0, 0, 0);
      acc1 = __builtin_amdgcn_mfma_f32_32x32x16_bf16(al, bh, acc1, 0, 0, 0);
      acc1 = __builtin_amdgcn_mfma_f32_32x32x16_bf16(al, bl, acc1, 0, 0, 0);
    }
  }

  int crow = kg << 2;
#pragma unroll
  for (int r = 0; r < 16; ++r) {
    int row = d0 + crow + (r & 3) + ((r >> 2) << 3);
    C[(size_t)row * 3072 + n0 + l31] = acc0[r];
    C[(size_t)row * 3072 + n0 + 32 + l31] = acc1[r];
  }
}

// ---- S5a: prefix-DFT over d + irfft phase, accumulate w_s * val into Htot ----
__global__ __launch_bounds__(192) void k_s5a(const float* __restrict__ mlpw, float* __restrict__ ws) {
  int bid = blockIdx.x;
  int s = bid >> 7;
  int rem = bid & 127;
  int x = rem >> 2;
  int tq = rem & 3;
  const int Ts[3] = {96, 192, 384};
  const int Ro[3] = {R0OFF, R1OFF, R2OFF};
  const int lpbase[3] = {288, 192, 0};
  int T = Ts[s];
  int Lc = T >> 3;
  __shared__ float cs[384][2];
  __shared__ float Lsr[8][24], Lsi[8][24];
  int tid = threadIdx.x;
  for (int e = tid; e < T; e += 192) {
    float th = 6.283185307179586f * (float)e / (float)T;
    cs[e][0] = cosf(th);
    cs[e][1] = sinf(th);
  }
  int c = tid / 24, tl = tid % 24;
  int t = tq * 24 + tl;
  const float* Rre = ws + Ro[s] + (size_t)x * 96 + t;
  const float* Rim = Rre + (size_t)T * 3072;
  float* Htot = ws + HTOTOFF;
  float wsc = mlpw[s];
  __syncthreads();
  int d0 = c * Lc;
  float zr = 0.f, zi = 0.f;
  for (int d = d0; d < d0 + Lc; ++d) {
    float rr = Rre[(size_t)d * 3072];
    float ri = Rim[(size_t)d * 3072];
    int e1 = (x * d) % T;
    float c1 = cs[e1][0], s1 = cs[e1][1];
    zr += c1 * rr + s1 * ri;
    zi += c1 * ri - s1 * rr;
  }
  Lsr[c][tl] = zr; Lsi[c][tl] = zi;
  __syncthreads();
  if (c == 0) {
    float pr = 0.f, pi = 0.f;
#pragma unroll
    for (int cc = 0; cc < 8; ++cc) {
      float lr = Lsr[cc][tl], li = Lsi[cc][tl];
      Lsr[cc][tl] = pr; Lsi[cc][tl] = pi;
      pr += lr; pi += li;
    }
  }
  __syncthreads();
  zr = Lsr[c][tl]; zi = Lsi[c][tl];
  float sc = (((x == 0) ? 1.f : 2.f) / (float)T) * wsc;
  for (int d = d0; d < d0 + Lc; ++d) {
    float rr = Rre[(size_t)d * 3072];
    float ri = Rim[(size_t)d * 3072];
    int e1 = (x * d) % T;
    float c1 = cs[e1][0], s1 = cs[e1][1];
    zr += c1 * rr + s1 * ri;
    zi += c1 * ri - s1 * rr;
    int k = T - 1 - d;
    int e2 = (x * (95 - k)) % T;
    if (e2 < 0) e2 += T;
    float c2 = cs[e2][0], s2 = cs[e2][1];
    atomicAdd(Htot + (size_t)(lpbase[s] + k) * 96 + t, sc * (c2 * zr - s2 * zi));
  }
}

// ---- S6: out[b,t,j] = sum_l x*Htot + mean*(1-S[t]) + std*mlp_b (stats fused) ----
__global__ __launch_bounds__(256) void k_s6(const float* __restrict__ xin, const float* __restrict__ mlpb_p,
                                            const float* __restrict__ ws, float* __restrict__ out) {
  int b = blockIdx.x >> 2, tq = blockIdx.x & 3;
  int tid = threadIdx.x;
  int j = tid & 63, tsub = tid >> 6;
  __shared__ float Ht[384 * 24];
  for (int idx = tid; idx < 384 * 24; idx += 256) {
    int lp = idx / 24, c = idx % 24;
    Ht[idx] = ws[HTOTOFF + lp * 96 + tq * 24 + c];
  }
  float ssum = 0.f, sq = 0.f;
#pragma unroll
  for (int p = 0; p < 12; ++p) {
    const float* src = ws + STATSP + (((size_t)b * 12 + p) * 64 + j) * 2;
    ssum += src[0]; sq += src[1];
  }
  float mn = ssum * (1.f / 720.f);
  float var = sq * (1.f / 720.f) - mn * mn;
  float sd = sqrtf(var + 1e-5f);
  __syncthreads();
  float mlpb = mlpb_p[0];
  float acc[6] = {0.f, 0.f, 0.f, 0.f, 0.f, 0.f};
  float accS[6] = {0.f, 0.f, 0.f, 0.f, 0.f, 0.f};
  const float* xp = xin + ((size_t)b * 720 + 336) * 64 + j;
  for (int lp = 0; lp < 384; ++lp) {
    float xv = xp[(size_t)lp * 64];
    const float* hr = &Ht[lp * 24 + tsub * 6];
    float2 h01 = *(const float2*)&hr[0];
    float2 h23 = *(const float2*)&hr[2];
    float2 h45 = *(const float2*)&hr[4];
    float hh[6] = {h01.x, h01.y, h23.x, h23.y, h45.x, h45.y};
#pragma unroll
    for (int u = 0; u < 6; ++u) {
      acc[u] += xv * hh[u];
      accS[u] += hh[u];
    }
  }
#pragma unroll
  for (int u = 0; u < 6; ++u) {
    int t = tq * 24 + tsub * 6 + u;
    float val = acc[u] + mn * (1.f - accS[u]) + sd * mlpb;
    out[((size_t)b * 96 + t) * 64 + j] = val;
  }
}

extern "C" void kernel_launch(void* const* d_in, const int* in_sizes, int n_in,
                              void* d_out, int out_size, void* d_ws, size_t ws_size,
                              hipStream_t stream) {
  const float* x  = (const float*)d_in[0];
  const float* wr = (const float*)d_in[1];
  const float* wi = (const float*)d_in[2];
  const float* mw = (const float*)d_in[3];
  const float* mb = (const float*)d_in[4];
  const float* Ab = (const float*)d_in[5];
  const float* Bb = (const float*)d_in[6];
  const float* ev = (const float*)d_in[7];
  float* wsf = (float*)d_ws;
  float* out = (float*)d_out;

  k_pre<<<1275, 256, 0, stream>>>(Ab, Bb, x, ev, wsf);

  const double* AD = (const double*)(wsf + WOFF) + AD64;
  double* PD = (double*)(wsf + WOFF) + PD64;
  double* KD = (double*)(wsf + WOFF) + KKD64;
  static const int Ts[3] = {96, 192, 384};
  static const int rowoff[3] = {0, 24576, 73728};
  static const int KKo[3] = {KKOFF0, KKOFF1, KKOFF2};

  // Fused doubling: round r extends KK rows [n, min(2n,T)) = KK[0,n) * P_n^T
  // (dual-written fp64 + packed-bf16) and squares P_n -> P_2n in the same launch.
  int have[3] = {1, 1, 1};
  for (int r = 0; r <= 8; ++r) {
    G64Jobs jb;
    jb.njobs = 0;
    int tiles = 0;
    for (int s = 0; s < 3; ++s) {
      int T = Ts[s];
      if (have[s] >= T) continue;
      const double* Pn = (r == 0) ? (AD + (size_t)s * 65536)
                                  : (PD + (size_t)(2 * s + (r & 1)) * 65536);
      int M = ((2 * have[s] < T) ? 2 * have[s] : T) - have[s];
      int q = jb.njobs++;
      jb.A[q] = KD + rowoff[s]; jb.B[q] = Pn;
      jb.C[q] = KD + rowoff[s] + (size_t)have[s] * 256;
      jb.CF[q] = wsf + KKo[s] + (size_t)have[s] * 256;
      jb.M[q] = M; jb.transB[q] = 1; jb.tile0[q] = tiles;
      tiles += ((M + 31) / 32) * 8;
      if (2 * have[s] < T) {
        q = jb.njobs++;
        jb.A[q] = Pn; jb.B[q] = Pn;
        jb.C[q] = PD + (size_t)(2 * s + ((r + 1) & 1)) * 65536;
        jb.CF[q] = nullptr;
        jb.M[q] = 256; jb.transB[q] = 0; jb.tile0[q] = tiles;
        tiles += 64;
      }
      have[s] = (2 * have[s] < T) ? 2 * have[s] : T;
    }
    if (jb.njobs) k_gemm64<<<tiles, 256, 0, stream>>>(jb);
  }

  k_s3<<<768, 384, 0, stream>>>(wr, wi, wsf);
  k_s4<<<504, 256, 0, stream>>>(wsf);
  k_s5a<<<384, 192, 0, stream>>>(mw, wsf);
  k_s6<<<64, 256, 0, stream>>>(x, mb, wsf, out);
}

// Round 5
// 372.846 us; speedup vs baseline: 1.0304x; 1.0304x over previous
//
#include <hip/hip_runtime.h>

typedef unsigned short u16;
typedef unsigned int u32;

typedef __bf16 bf16x8 __attribute__((ext_vector_type(8)));
typedef unsigned short ushort8 __attribute__((ext_vector_type(8)));
typedef float f32x16 __attribute__((ext_vector_type(16)));

// workspace offsets (in floats)
#define STATSP 2048     // 16*12*64*2 = 24576 floats of stats partials
#define EPOFF 32768     // E split tables: [hi: 73728 u16][lo: 73728 u16] (same bytes as before)
#define KKOFF0 591872
#define KKOFF1 616448
#define KKOFF2 665600
#define WOFF 763904
#define R0OFF 5482496
#define R1OFF 6072320
#define R2OFF 7251968
#define HTOTOFF 11675648
// total = 11712512 floats = ~46.9 MB
// fp64 chain scratch lives INSIDE the Wtil region [WOFF, R0OFF); it is fully
// consumed before k_s3 overwrites Wtil. Offsets in doubles relative to
// (double*)(ws + WOFF):
#define AD64 0        // 3*65536 doubles  (Ad fp64, per scale)
#define PD64 196608   // 6*65536 doubles  (P ping-pong, per scale)
#define KKD64 589824  // 672*256 doubles  (KK rows: s0 96, s1 192, s2 384)
// KK (packed hi/lo u32) lives at KKOFF* ; Wtil2 (packed u32, layout
// [i>>3][n][i&7], n = x*96+t) lives at WOFF + jidx*786432 (u32 view).

// float -> packed u32: low16 = bf16 RNE of a, high16 = bf16 (trunc) of residual
__device__ __forceinline__ u32 pack_hl(float a) {
  u32 bits = __builtin_bit_cast(u32, a);
  u32 hi = (bits + 0x7fffu + ((bits >> 16) & 1u)) >> 16;
  float hif = __builtin_bit_cast(float, hi << 16);
  float r = a - hif;
  u32 lo = __builtin_bit_cast(u32, r) >> 16;
  return hi | (lo << 16);
}

__device__ __forceinline__ void unpk8(const u32* p, bf16x8& h, bf16x8& l) {
  ushort8 hu, lu;
#pragma unroll
  for (int j = 0; j < 8; ++j) {
    u32 v = p[j];
    hu[j] = (unsigned short)(v & 0xffffu);
    lu[j] = (unsigned short)(v >> 16);
  }
  h = __builtin_bit_cast(bf16x8, hu);
  l = __builtin_bit_cast(bf16x8, lu);
}

// async global->LDS, 16B per lane; LDS dest is wave-uniform base + lane*16
__device__ __forceinline__ void gload_lds16(const float* g, float* l) {
  __builtin_amdgcn_global_load_lds(
      (const __attribute__((address_space(1))) void*)g,
      (__attribute__((address_space(3))) void*)l, 16, 0, 0);
}

// ---- k_pre: A->fp64, seed KK row0, stats1, zero Htot, pack E hi/lo ----
__global__ __launch_bounds__(256) void k_pre(const float* __restrict__ Ab,
                                             const float* __restrict__ Bb,
                                             const float* __restrict__ xin,
                                             const float* __restrict__ ev,
                                             float* __restrict__ ws) {
  __shared__ float rs[4][64], rq[4][64];
  int blk = blockIdx.x, tid = threadIdx.x;
  if (blk < 771) {
    double* dws = (double*)(ws + WOFF);
    int idx = blk * 256 + tid;
    if (idx < 196608) {
      dws[AD64 + idx] = (double)Ab[idx];
    } else {
      int g = idx - 196608;  // 0..767 (grid sized exactly)
      const int rowoff[3] = {0, 24576, 73728};
      const int kko[3] = {KKOFF0, KKOFF1, KKOFF2};
      int s = g >> 8, i = g & 255;
      float v = Bb[g];
      dws[KKD64 + rowoff[s] + i] = (double)v;
      ((u32*)ws)[kko[s] + i] = pack_hl(v);
    }
  } else if (blk < 963) {
    int b2 = blk - 771;  // 0..191
    int b = b2 / 12, part = b2 % 12;
    int j = tid & 63, g = tid >> 6;
    const float* xp = xin + ((size_t)b * 720 + part * 60 + g) * 64 + j;
    float sum = 0.f, ss = 0.f;
#pragma unroll
    for (int i = 0; i < 15; ++i) {
      float v = xp[(size_t)i * 256];
      sum += v; ss += v * v;
    }
    rs[g][j] = sum; rq[g][j] = ss;
    __syncthreads();
    if (g == 0) {
      float s = rs[0][j] + rs[1][j] + rs[2][j] + rs[3][j];
      float q = rq[0][j] + rq[1][j] + rq[2][j] + rq[3][j];
      float* dst = ws + STATSP + ((size_t)b2 * 64 + j) * 2;
      dst[0] = s; dst[1] = q;
    }
  } else if (blk < 987) {
    int idx = (blk - 963) * 256 + tid;
    for (; idx < 36864; idx += 24 * 256) ws[HTOTOFF + idx] = 0.f;
  } else {
    // E pack: ev [3][96][256] -> SPLIT u16 tables: hi[idx], lo[73728+idx]
    int idx = (blk - 987) * 256 + tid;  // 0..73727 (288 blocks exactly)
    u32 ph = pack_hl(ev[idx]);
    u16* eb = (u16*)((u32*)ws + EPOFF);
    eb[idx] = (u16)(ph & 0xffffu);
    eb[73728 + idx] = (u16)(ph >> 16);
  }
}

// ---- fp64 chain GEMM, 32x32 tiles, 2x2 micro, K=N=256, register prefetch ----
struct G64Jobs {
  const double* A[8]; const double* B[8]; double* C[8]; float* CF[8];
  int M[8]; int transB[8]; int tile0[8];
  int njobs;
};

__global__ __launch_bounds__(256) void k_gemm64(G64Jobs jb) {
  int bid = blockIdx.x;
  int j = 0;
  for (int q = 1; q < jb.njobs; ++q) if (bid >= jb.tile0[q]) j = q;
  int local = bid - jb.tile0[j];
  int tm = local >> 3, tn = local & 7;
  const double* A = jb.A[j];
  const double* Bm = jb.B[j];
  double* C = jb.C[j];
  float* CF = jb.CF[j];
  int M = jb.M[j], tB = jb.transB[j];
  int row0 = tm * 32, col0 = tn * 32;
  __shared__ double As[32][33], Bs[32][33];
  int tid = threadIdx.x;
  int ty = tid >> 4, tx = tid & 15;
  int lr = tid >> 3, lk = (tid & 7) << 2;
  double va[4], vb[4];
#pragma unroll
  for (int u = 0; u < 4; ++u) {
    va[u] = (row0 + lr < M) ? A[(size_t)(row0 + lr) * 256 + lk + u] : 0.0;
    vb[u] = tB ? Bm[(size_t)(col0 + lr) * 256 + lk + u]
               : Bm[(size_t)lr * 256 + col0 + lk + u];
  }
  double a00 = 0., a01 = 0., a10 = 0., a11 = 0.;
  for (int kc = 0; kc < 256; kc += 32) {
#pragma unroll
    for (int u = 0; u < 4; ++u) {
      As[lr][lk + u] = va[u];
      if (tB) Bs[lk + u][lr] = vb[u];
      else    Bs[lr][lk + u] = vb[u];
    }
    __syncthreads();
    if (kc < 224) {
      int kn = kc + 32;
#pragma unroll
      for (int u = 0; u < 4; ++u) {
        va[u] = (row0 + lr < M) ? A[(size_t)(row0 + lr) * 256 + kn + lk + u] : 0.0;
        vb[u] = tB ? Bm[(size_t)(col0 + lr) * 256 + kn + lk + u]
                   : Bm[(size_t)(kn + lr) * 256 + col0 + lk + u];
      }
    }
#pragma unroll 8
    for (int k = 0; k < 32; ++k) {
      double x0 = As[2 * ty][k], x1 = As[2 * ty + 1][k];
      double y0 = Bs[k][2 * tx], y1 = Bs[k][2 * tx + 1];
      a00 = fma(x0, y0, a00); a01 = fma(x0, y1, a01);
      a10 = fma(x1, y0, a10); a11 = fma(x1, y1, a11);
    }
    __syncthreads();
  }
  int r0 = row0 + 2 * ty, c0 = col0 + 2 * tx;
  if (r0 < M) {
    C[(size_t)r0 * 256 + c0] = a00; C[(size_t)r0 * 256 + c0 + 1] = a01;
    if (CF) {
      ((u32*)CF)[(size_t)r0 * 256 + c0] = pack_hl((float)a00);
      ((u32*)CF)[(size_t)r0 * 256 + c0 + 1] = pack_hl((float)a01);
    }
  }
  if (r0 + 1 < M) {
    C[(size_t)(r0 + 1) * 256 + c0] = a10; C[(size_t)(r0 + 1) * 256 + c0 + 1] = a11;
    if (CF) {
      ((u32*)CF)[(size_t)(r0 + 1) * 256 + c0] = pack_hl((float)a10);
      ((u32*)CF)[(size_t)(r0 + 1) * 256 + c0 + 1] = pack_hl((float)a11);
    }
  }
}

// ---- S3 (MFMA split-bf16, global_load_lds 2-phase): Wtil = w x E^T ----
// R2/R3/R4 all hit a 42-54us latency wall: in-flight data lived in VGPRs and
// the allocator refused to fund them (VGPR_Count 44-72) -> loads serialized
// behind vmcnt(0). Fix: in-flight data lives in LDS via async
// global_load_lds (zero VGPR cost). Double-buffered 8KB chunks
// [2 i][32 o][32 x] f32, one vmcnt-drain barrier per chunk (m97 2-phase).
// Waves = (il, f): one i-row, one 32-t fragment, full K=256, acc = 1 f32x16.
// A split to bf16 hi/lo via native casts (v_cvt_pk); B (E) pre-split into
// separate hi/lo bf16 tables -> direct 16B loads, zero unpack.
// Output PACKED (hi|lo u32), layout Wtil2[i>>3][n][i&7], n=x*96+t.
__global__ __launch_bounds__(384, 5) void k_s3(const float* __restrict__ wr,
                                               const float* __restrict__ wi,
                                               float* __restrict__ ws) {
  __shared__ float stage[2][2048];   // 16 KB A staging
  __shared__ u32 pairs[3 * 1056];    // 12.7 KB epilogue pairing
  int bid = blockIdx.x;
  int jidx = bid >> 7;
  int r127 = bid & 127;
  int mb = ((r127 & 7) << 4) | (r127 >> 3);  // XCD-group swizzle (bijective)
  int s = jidx >> 1, p = jidx & 1;
  const float* w = (p ? wi : wr) + (size_t)s * 2097152;
  const u16* ebase = (const u16*)((const u32*)ws + EPOFF);
  const u16* eh = ebase + (size_t)s * 24576;
  const u16* el = ebase + 73728 + (size_t)s * 24576;
  int i0 = mb * 2;
  int tid = threadIdx.x;
  int lane = tid & 63;
  int wid = tid >> 6;
  int il = wid & 1, f = wid >> 1;

  int tcol = lane & 31;          // A row (x) / B col (t within f) / D col
  int og8 = (lane >> 5) << 3;    // k sub-group (which 8 of 16 k)
  const u16* bhp = eh + (size_t)(f * 32 + tcol) * 256 + og8;
  const u16* blp = el + (size_t)(f * 32 + tcol) * 256 + og8;

  // staging decode (waves 0..3, 2 instrs each): linear float idx in chunk =
  // qq*256 + lane*4 -> [i_l][o_l][x] with chunk layout [2][32][32]
  bool stager = (wid < 4);
  int sq0 = wid * 2;
  int s_i[2], s_o[2], s_x[2];
#pragma unroll
  for (int j = 0; j < 2; ++j) {
    int qq = sq0 + j;
    s_i[j] = qq >> 2;
    s_o[j] = (qq & 3) * 8 + (lane >> 3);
    s_x[j] = (lane & 7) * 4;
  }

  f32x16 acc;
#pragma unroll
  for (int r = 0; r < 16; ++r) acc[r] = 0.f;

  // prologue: stage chunk 0 -> buf 0
  if (stager) {
#pragma unroll
    for (int j = 0; j < 2; ++j) {
      const float* g = w + (((size_t)(i0 + s_i[j]) * 256 + s_o[j]) << 5) + s_x[j];
      gload_lds16(g, &stage[0][(sq0 + j) * 256]);
    }
  }
  __syncthreads();

#pragma unroll 2
  for (int c = 0; c < 8; ++c) {
    int buf = c & 1;
    if (c < 7 && stager) {  // stage next chunk into the other buffer
      int kon = (c + 1) * 32;
#pragma unroll
      for (int j = 0; j < 2; ++j) {
        const float* g = w + (((size_t)(i0 + s_i[j]) * 256 + kon + s_o[j]) << 5) + s_x[j];
        gload_lds16(g, &stage[buf ^ 1][(sq0 + j) * 256]);
      }
    }
    int ko = c * 32;
#pragma unroll
    for (int ks = 0; ks < 2; ++ks) {
      int ob = ks * 16 + og8;
      float fa[8];
#pragma unroll
      for (int j = 0; j < 8; ++j)
        fa[j] = stage[buf][il * 1024 + (ob + j) * 32 + tcol];
      bf16x8 ah, al;
#pragma unroll
      for (int j = 0; j < 8; ++j) {
        __bf16 h = (__bf16)fa[j];
        ah[j] = h;
        al[j] = (__bf16)(fa[j] - (float)h);
      }
      bf16x8 bh = *(const bf16x8*)(bhp + ko + ks * 16);
      bf16x8 bl = *(const bf16x8*)(blp + ko + ks * 16);
      acc = __builtin_amdgcn_mfma_f32_32x32x16_bf16(ah, bh, acc, 0, 0, 0);
      acc = __builtin_amdgcn_mfma_f32_32x32x16_bf16(ah, bl, acc, 0, 0, 0);
      acc = __builtin_amdgcn_mfma_f32_32x32x16_bf16(al, bh, acc, 0, 0, 0);
    }
    __syncthreads();  // buf consumed + staged next drained (vmcnt0+barrier)
  }

  // pack own values; pair il=0/il=1 through LDS; il=1 stores uint2
  int x0 = (lane >> 5) << 2;
  u32 mine[16];
#pragma unroll
  for (int r = 0; r < 16; ++r) mine[r] = pack_hl(acc[r]);
  if (il == 0) {
#pragma unroll
    for (int r = 0; r < 16; ++r) {
      int row = x0 + (r & 3) + ((r >> 2) << 3);
      pairs[f * 1056 + row * 33 + tcol] = mine[r];
    }
  }
  __syncthreads();
  if (il == 1) {
    u32* W2 = (u32*)(ws + WOFF) + (size_t)jidx * 786432 +
              (size_t)(mb >> 2) * 24576 + ((mb & 3) << 1);
#pragma unroll
    for (int r = 0; r < 16; ++r) {
      int row = x0 + (r & 3) + ((r >> 2) << 3);
      uint2 st;
      st.x = pairs[f * 1056 + row * 33 + tcol];
      st.y = mine[r];
      *(uint2*)(W2 + (size_t)(row * 96 + f * 32 + tcol) * 8) = st;
    }
  }
}

// ---- S4 (MFMA split-bf16, zero-LDS): R[d,n] = sum_i KK[d,i]*Wtil[i,n] ----
// A = packed KK [T][256] (k-contiguous), B = Wtil2 [i>>3][n][i&7]
// (k-contiguous within each 8-group). Both fragments are direct 32B global
// reads (L2-resident). Block = 32 d x 256 n, 4 waves (one 64-n slice each).
__global__ __launch_bounds__(256) void k_s4(float* __restrict__ ws) {
  int bid = blockIdx.x;
  const int cums[6] = {0, 36, 72, 144, 216, 360};  // tiles: (T/32)*12 per (s,p)
  int jidx = 0;
#pragma unroll
  for (int q = 1; q < 6; ++q) if (bid >= cums[q]) jidx = q;
  int local = bid - cums[jidx];
  int s = jidx >> 1, p = jidx & 1;
  const int Ts[3] = {96, 192, 384};
  const int KKo[3] = {KKOFF0, KKOFF1, KKOFF2};
  const int Ro[3] = {R0OFF, R1OFF, R2OFF};
  int T = Ts[s];
  int td = local / 12, tn = local % 12;
  int d0 = td * 32;
  int tid = threadIdx.x;
  int lane = tid & 63, wid = tid >> 6;
  int n0 = tn * 256 + wid * 64;
  int l31 = lane & 31, kg = lane >> 5;
  const u32* Ap = (const u32*)ws + KKo[s] + (size_t)(d0 + l31) * 256 + kg * 8;
  const u32* Bp = (const u32*)ws + WOFF + (size_t)jidx * 786432 + (size_t)kg * 24576;
  const u32* b0p = Bp + (size_t)(n0 + l31) * 8;
  const u32* b1p = Bp + (size_t)(n0 + 32 + l31) * 8;
  float* C = ws + Ro[s] + (size_t)p * T * 3072;

  f32x16 acc0, acc1;
#pragma unroll
  for (int r = 0; r < 16; ++r) { acc0[r] = 0.f; acc1[r] = 0.f; }

#pragma unroll 2
  for (int ks = 0; ks < 16; ++ks) {
    uint4 a0 = *(const uint4*)(Ap + ks * 16);
    uint4 a1 = *(const uint4*)(Ap + ks * 16 + 4);
    size_t bo = (size_t)ks * 49152;  // 2 groups of 8 i per kstep
    uint4 x0 = *(const uint4*)(b0p + bo);
    uint4 x1 = *(const uint4*)(b0p + bo + 4);
    uint4 y0 = *(const uint4*)(b1p + bo);
    uint4 y1 = *(const uint4*)(b1p + bo + 4);
    u32 ap[8] = {a0.x, a0.y, a0.z, a0.w, a1.x, a1.y, a1.z, a1.w};
    bf16x8 ah, al;
    unpk8(ap, ah, al);
    {
      u32 bp[8] = {x0.x, x0.y, x0.z, x0.w, x1.x, x1.y, x1.z, x1.w};
      bf16x8 bh, bl;
      unpk8(bp, bh, bl);
      acc0 = __builtin_amdgcn_mfma_f32_32x32x16_bf16(ah, bh, acc0, 0, 0, 0);
      acc0 = __builtin_amdgcn_mfma_f32_32x32x16_bf16(ah, bl, acc0, 0, 0, 0);
      acc0 = __builtin_amdgcn_mfma_f32_32x32x16_bf16(al, bh, acc0, 0, 0, 0);
      acc0 = __builtin_amdgcn_mfma_f32_32x32x16_bf16(al, bl, acc0, 0, 0, 0);
    }
    {
      u32 bp[8] = {y0.x, y0.y, y0.z, y0.w, y1.x, y1.y, y1.z, y1.w};
      bf16x8 bh, bl;
      unpk8(bp, bh, bl);
      acc1 = __builtin_amdgcn_mfma_f32_32x32x16_bf16(ah, bh, acc1, 0, 0, 0);
      acc1 = __builtin_amdgcn_mfma_f32_32x32x16_bf16(ah, bl, acc1, 0, 0, 0);
      acc1 = __builtin_amdgcn_mfma_f32_32x32x16_bf16(al, bh, acc1, 0, 0, 0);
      acc1 = __builtin_amdgcn_mfma_f32_32x32x16_bf16(al, bl, acc1, 0, 0, 0);
    }
  }

  int crow = kg << 2;
#pragma unroll
  for (int r = 0; r < 16; ++r) {
    int row = d0 + crow + (r & 3) + ((r >> 2) << 3);
    C[(size_t)row * 3072 + n0 + l31] = acc0[r];
    C[(size_t)row * 3072 + n0 + 32 + l31] = acc1[r];
  }
}

// ---- S5a: prefix-DFT over d + irfft phase, accumulate w_s * val into Htot ----
__global__ __launch_bounds__(192) void k_s5a(const float* __restrict__ mlpw, float* __restrict__ ws) {
  int bid = blockIdx.x;
  int s = bid >> 7;
  int rem = bid & 127;
  int x = rem >> 2;
  int tq = rem & 3;
  const int Ts[3] = {96, 192, 384};
  const int Ro[3] = {R0OFF, R1OFF, R2OFF};
  const int lpbase[3] = {288, 192, 0};
  int T = Ts[s];
  int Lc = T >> 3;
  __shared__ float cs[384][2];
  __shared__ float Lsr[8][24], Lsi[8][24];
  int tid = threadIdx.x;
  for (int e = tid; e < T; e += 192) {
    float th = 6.283185307179586f * (float)e / (float)T;
    cs[e][0] = cosf(th);
    cs[e][1] = sinf(th);
  }
  int c = tid / 24, tl = tid % 24;
  int t = tq * 24 + tl;
  const float* Rre = ws + Ro[s] + (size_t)x * 96 + t;
  const float* Rim = Rre + (size_t)T * 3072;
  float* Htot = ws + HTOTOFF;
  float wsc = mlpw[s];
  __syncthreads();
  int d0 = c * Lc;
  float zr = 0.f, zi = 0.f;
  for (int d = d0; d < d0 + Lc; ++d) {
    float rr = Rre[(size_t)d * 3072];
    float ri = Rim[(size_t)d * 3072];
    int e1 = (x * d) % T;
    float c1 = cs[e1][0], s1 = cs[e1][1];
    zr += c1 * rr + s1 * ri;
    zi += c1 * ri - s1 * rr;
  }
  Lsr[c][tl] = zr; Lsi[c][tl] = zi;
  __syncthreads();
  if (c == 0) {
    float pr = 0.f, pi = 0.f;
#pragma unroll
    for (int cc = 0; cc < 8; ++cc) {
      float lr = Lsr[cc][tl], li = Lsi[cc][tl];
      Lsr[cc][tl] = pr; Lsi[cc][tl] = pi;
      pr += lr; pi += li;
    }
  }
  __syncthreads();
  zr = Lsr[c][tl]; zi = Lsi[c][tl];
  float sc = (((x == 0) ? 1.f : 2.f) / (float)T) * wsc;
  for (int d = d0; d < d0 + Lc; ++d) {
    float rr = Rre[(size_t)d * 3072];
    float ri = Rim[(size_t)d * 3072];
    int e1 = (x * d) % T;
    float c1 = cs[e1][0], s1 = cs[e1][1];
    zr += c1 * rr + s1 * ri;
    zi += c1 * ri - s1 * rr;
    int k = T - 1 - d;
    int e2 = (x * (95 - k)) % T;
    if (e2 < 0) e2 += T;
    float c2 = cs[e2][0], s2 = cs[e2][1];
    atomicAdd(Htot + (size_t)(lpbase[s] + k) * 96 + t, sc * (c2 * zr - s2 * zi));
  }
}

// ---- S6: out[b,t,j] = sum_l x*Htot + mean*(1-S[t]) + std*mlp_b (stats fused) ----
__global__ __launch_bounds__(256) void k_s6(const float* __restrict__ xin, const float* __restrict__ mlpb_p,
                                            const float* __restrict__ ws, float* __restrict__ out) {
  int b = blockIdx.x >> 2, tq = blockIdx.x & 3;
  int tid = threadIdx.x;
  int j = tid & 63, tsub = tid >> 6;
  __shared__ float Ht[384 * 24];
  for (int idx = tid; idx < 384 * 24; idx += 256) {
    int lp = idx / 24, c = idx % 24;
    Ht[idx] = ws[HTOTOFF + lp * 96 + tq * 24 + c];
  }
  float ssum = 0.f, sq = 0.f;
#pragma unroll
  for (int p = 0; p < 12; ++p) {
    const float* src = ws + STATSP + (((size_t)b * 12 + p) * 64 + j) * 2;
    ssum += src[0]; sq += src[1];
  }
  float mn = ssum * (1.f / 720.f);
  float var = sq * (1.f / 720.f) - mn * mn;
  float sd = sqrtf(var + 1e-5f);
  __syncthreads();
  float mlpb = mlpb_p[0];
  float acc[6] = {0.f, 0.f, 0.f, 0.f, 0.f, 0.f};
  float accS[6] = {0.f, 0.f, 0.f, 0.f, 0.f, 0.f};
  const float* xp = xin + ((size_t)b * 720 + 336) * 64 + j;
  for (int lp = 0; lp < 384; ++lp) {
    float xv = xp[(size_t)lp * 64];
    const float* hr = &Ht[lp * 24 + tsub * 6];
    float2 h01 = *(const float2*)&hr[0];
    float2 h23 = *(const float2*)&hr[2];
    float2 h45 = *(const float2*)&hr[4];
    float hh[6] = {h01.x, h01.y, h23.x, h23.y, h45.x, h45.y};
#pragma unroll
    for (int u = 0; u < 6; ++u) {
      acc[u] += xv * hh[u];
      accS[u] += hh[u];
    }
  }
#pragma unroll
  for (int u = 0; u < 6; ++u) {
    int t = tq * 24 + tsub * 6 + u;
    float val = acc[u] + mn * (1.f - accS[u]) + sd * mlpb;
    out[((size_t)b * 96 + t) * 64 + j] = val;
  }
}

extern "C" void kernel_launch(void* const* d_in, const int* in_sizes, int n_in,
                              void* d_out, int out_size, void* d_ws, size_t ws_size,
                              hipStream_t stream) {
  const float* x  = (const float*)d_in[0];
  const float* wr = (const float*)d_in[1];
  const float* wi = (const float*)d_in[2];
  const float* mw = (const float*)d_in[3];
  const float* mb = (const float*)d_in[4];
  const float* Ab = (const float*)d_in[5];
  const float* Bb = (const float*)d_in[6];
  const float* ev = (const float*)d_in[7];
  float* wsf = (float*)d_ws;
  float* out = (float*)d_out;

  k_pre<<<1275, 256, 0, stream>>>(Ab, Bb, x, ev, wsf);

  const double* AD = (const double*)(wsf + WOFF) + AD64;
  double* PD = (double*)(wsf + WOFF) + PD64;
  double* KD = (double*)(wsf + WOFF) + KKD64;
  static const int Ts[3] = {96, 192, 384};
  static const int rowoff[3] = {0, 24576, 73728};
  static const int KKo[3] = {KKOFF0, KKOFF1, KKOFF2};

  // Fused doubling: round r extends KK rows [n, min(2n,T)) = KK[0,n) * P_n^T
  // (dual-written fp64 + packed-bf16) and squares P_n -> P_2n in the same launch.
  int have[3] = {1, 1, 1};
  for (int r = 0; r <= 8; ++r) {
    G64Jobs jb;
    jb.njobs = 0;
    int tiles = 0;
    for (int s = 0; s < 3; ++s) {
      int T = Ts[s];
      if (have[s] >= T) continue;
      const double* Pn = (r == 0) ? (AD + (size_t)s * 65536)
                                  : (PD + (size_t)(2 * s + (r & 1)) * 65536);
      int M = ((2 * have[s] < T) ? 2 * have[s] : T) - have[s];
      int q = jb.njobs++;
      jb.A[q] = KD + rowoff[s]; jb.B[q] = Pn;
      jb.C[q] = KD + rowoff[s] + (size_t)have[s] * 256;
      jb.CF[q] = wsf + KKo[s] + (size_t)have[s] * 256;
      jb.M[q] = M; jb.transB[q] = 1; jb.tile0[q] = tiles;
      tiles += ((M + 31) / 32) * 8;
      if (2 * have[s] < T) {
        q = jb.njobs++;
        jb.A[q] = Pn; jb.B[q] = Pn;
        jb.C[q] = PD + (size_t)(2 * s + ((r + 1) & 1)) * 65536;
        jb.CF[q] = nullptr;
        jb.M[q] = 256; jb.transB[q] = 0; jb.tile0[q] = tiles;
        tiles += 64;
      }
      have[s] = (2 * have[s] < T) ? 2 * have[s] : T;
    }
    if (jb.njobs) k_gemm64<<<tiles, 256, 0, stream>>>(jb);
  }

  k_s3<<<768, 384, 0, stream>>>(wr, wi, wsf);
  k_s4<<<504, 256, 0, stream>>>(wsf);
  k_s5a<<<384, 192, 0, stream>>>(mw, wsf);
  k_s6<<<64, 256, 0, stream>>>(x, mb, wsf, out);
}

// Round 6
// 330.448 us; speedup vs baseline: 1.1626x; 1.1283x over previous
//
#include <hip/hip_runtime.h>

typedef unsigned short u16;
typedef unsigned int u32;

typedef __bf16 bf16x8 __attribute__((ext_vector_type(8)));
typedef unsigned short ushort8 __attribute__((ext_vector_type(8)));
typedef float f32x16 __attribute__((ext_vector_type(16)));

// workspace offsets (in floats)
#define STATSP 2048     // 16*12*64*2 = 24576 floats of stats partials
#define EPOFF 32768     // E split tables: [hi: 73728 u16][lo: 73728 u16]
#define KKOFF0 591872
#define KKOFF1 616448
#define KKOFF2 665600
#define WOFF 763904
#define R0OFF 5482496
#define R1OFF 6072320
#define R2OFF 7251968
#define HTOTOFF 11675648
// total = 11712512 floats = ~46.9 MB
// fp64 chain scratch lives INSIDE the Wtil region [WOFF, R0OFF); it is fully
// consumed (k_pack) before k_s3 overwrites Wtil. Offsets in doubles relative
// to (double*)(ws + WOFF):
#define AD64 0        // 3*65536 doubles  (Ad fp64, per scale)
#define PD64 196608   // 9*65536 doubles  (P TRIPLE-buffer: (s*3+b)*65536)
#define KKD64 786432  // 672*256 doubles  (KK rows fp64: s0 96, s1 192, s2 384)
// KK (packed hi/lo u32) lives at KKOFF*; Wtil2 (packed u32, layout
// [i>>3][n][i&7], n = x*96+t) lives at WOFF + jidx*786432 (u32 view).

// float -> packed u32: low16 = bf16 RNE of a, high16 = bf16 of residual
__device__ __forceinline__ u32 pack_hl(float a) {
  u32 bits = __builtin_bit_cast(u32, a);
  u32 hi = (bits + 0x7fffu + ((bits >> 16) & 1u)) >> 16;
  float hif = __builtin_bit_cast(float, hi << 16);
  float r = a - hif;
  u32 lo = __builtin_bit_cast(u32, r) >> 16;
  return hi | (lo << 16);
}

__device__ __forceinline__ void unpk8(const u32* p, bf16x8& h, bf16x8& l) {
  ushort8 hu, lu;
#pragma unroll
  for (int j = 0; j < 8; ++j) {
    u32 v = p[j];
    hu[j] = (unsigned short)(v & 0xffffu);
    lu[j] = (unsigned short)(v >> 16);
  }
  h = __builtin_bit_cast(bf16x8, hu);
  l = __builtin_bit_cast(bf16x8, lu);
}

// async global->LDS, 16B per lane; LDS dest is wave-uniform base + lane*16
__device__ __forceinline__ void gload_lds16(const float* g, float* l) {
  __builtin_amdgcn_global_load_lds(
      (const __attribute__((address_space(1))) void*)g,
      (__attribute__((address_space(3))) void*)l, 16, 0, 0);
}

// ---- k_pre: A->fp64, seed KK row0, stats1, zero Htot/PD0/KD, pack E ----
__global__ __launch_bounds__(256) void k_pre(const float* __restrict__ Ab,
                                             const float* __restrict__ Bb,
                                             const float* __restrict__ xin,
                                             const float* __restrict__ ev,
                                             float* __restrict__ ws) {
  __shared__ float rs[4][64], rq[4][64];
  int blk = blockIdx.x, tid = threadIdx.x;
  if (blk < 771) {
    double* dws = (double*)(ws + WOFF);
    int idx = blk * 256 + tid;
    if (idx < 196608) {
      dws[AD64 + idx] = (double)Ab[idx];
    } else {
      int g = idx - 196608;  // 0..767 (grid sized exactly)
      const int rowoff[3] = {0, 24576, 73728};
      int s = g >> 8, i = g & 255;
      dws[KKD64 + rowoff[s] + i] = (double)Bb[g];
    }
  } else if (blk < 963) {
    int b2 = blk - 771;  // 0..191
    int b = b2 / 12, part = b2 % 12;
    int j = tid & 63, g = tid >> 6;
    const float* xp = xin + ((size_t)b * 720 + part * 60 + g) * 64 + j;
    float sum = 0.f, ss = 0.f;
#pragma unroll
    for (int i = 0; i < 15; ++i) {
      float v = xp[(size_t)i * 256];
      sum += v; ss += v * v;
    }
    rs[g][j] = sum; rq[g][j] = ss;
    __syncthreads();
    if (g == 0) {
      float s = rs[0][j] + rs[1][j] + rs[2][j] + rs[3][j];
      float q = rq[0][j] + rq[1][j] + rq[2][j] + rq[3][j];
      float* dst = ws + STATSP + ((size_t)b2 * 64 + j) * 2;
      dst[0] = s; dst[1] = q;
    }
  } else if (blk < 987) {
    int idx = (blk - 963) * 256 + tid;
    for (; idx < 36864; idx += 24 * 256) ws[HTOTOFF + idx] = 0.f;
  } else if (blk < 1275) {
    // E pack: ev [3][96][256] -> SPLIT u16 tables: hi[idx], lo[73728+idx]
    int idx = (blk - 987) * 256 + tid;  // 0..73727 (288 blocks exactly)
    u32 ph = pack_hl(ev[idx]);
    u16* eb = (u16*)((u32*)ws + EPOFF);
    eb[idx] = (u16)(ph & 0xffffu);
    eb[73728 + idx] = (u16)(ph >> 16);
  } else if (blk < 1467) {
    // zero PD buf0 for each scale (dst of chain round 0)
    int g0 = ((blk - 1275) * 256 + tid) * 4;  // 0..196607, 192 blocks
    int s = g0 >> 16, off = g0 & 65535;
    double* dst = (double*)(ws + WOFF) + PD64 + (size_t)(s * 3) * 65536 + off;
    dst[0] = 0.; dst[1] = 0.; dst[2] = 0.; dst[3] = 0.;
  } else {
    // zero KD fp64 rows EXCEPT each scale's seeded row 0
    int g0 = ((blk - 1467) * 256 + tid) * 4;  // 0..172031, 168 blocks
    int local = (g0 < 24576) ? g0 : (g0 < 73728 ? g0 - 24576 : g0 - 73728);
    if (local >= 256) {
      double* dst = (double*)(ws + WOFF) + KKD64 + g0;
      dst[0] = 0.; dst[1] = 0.; dst[2] = 0.; dst[3] = 0.;
    }
  }
}

// ---- fp64 chain kernel: lean 32x32 tiles x 4-way K-split, atomic combine ----
// Old k_gemm64 ran the 256^3 squaring as 64 blocks (3/4 of chip idle) with an
// LDS-bound 8-chunk barrier loop -> ~12us/launch x 9 serial launches. Now:
// tile = 32x32 out, K=64 per block (kq = 0..3), ONE 33KB LDS stage + ONE
// barrier, 2x2 micro, fp64 atomics for the K-combine. Squaring = 256 blocks.
// transB: 0 = plain (P*P), 1 = B^T (KK*P^T), 2 = zero-job (pre-zero the
// buffer round r+1 accumulates into; src/dst/free are distinct mod 3).
struct CJobs {
  const double* A[12]; const double* B[12]; double* C[12];
  int M[12]; int transB[12]; int tile0[12];
  int njobs;
};

__global__ __launch_bounds__(256) void k_chain(CJobs jb) {
  int bid = blockIdx.x;
  int j = 0;
  for (int q = 1; q < jb.njobs; ++q) if (bid >= jb.tile0[q]) j = q;
  int local = bid - jb.tile0[j];
  int tB = jb.transB[j];
  int tid = threadIdx.x;
  if (tB == 2) {  // zero job: 64 tiles x 1024 doubles
    double* Z = jb.C[j] + (size_t)local * 1024 + tid * 4;
    Z[0] = 0.; Z[1] = 0.; Z[2] = 0.; Z[3] = 0.;
    return;
  }
  int M = jb.M[j];
  const double* A = jb.A[j];
  const double* Bm = jb.B[j];
  double* C = jb.C[j];
  int kq = local & 3, tn = (local >> 2) & 7, tm = local >> 5;
  int row0 = tm * 32, col0 = tn * 32, k0 = kq * 64;
  __shared__ double As[32][65];
  __shared__ double Bs[64][33];
  {
    int r = tid >> 3, k8 = (tid & 7) << 3;
    if (row0 + r < M) {
      const double* src = A + (size_t)(row0 + r) * 256 + k0 + k8;
#pragma unroll
      for (int u = 0; u < 8; ++u) As[r][k8 + u] = src[u];
    } else {
#pragma unroll
      for (int u = 0; u < 8; ++u) As[r][k8 + u] = 0.0;
    }
  }
  if (tB == 0) {
    int k = tid >> 2, c8 = (tid & 3) << 3;
    const double* src = Bm + (size_t)(k0 + k) * 256 + col0 + c8;
#pragma unroll
    for (int u = 0; u < 8; ++u) Bs[k][c8 + u] = src[u];
  } else {
    int c = tid >> 3, k8 = (tid & 7) << 3;
    const double* src = Bm + (size_t)(col0 + c) * 256 + k0 + k8;
#pragma unroll
    for (int u = 0; u < 8; ++u) Bs[k8 + u][c] = src[u];
  }
  __syncthreads();
  int ty = tid >> 4, tx = tid & 15;
  double a00 = 0., a01 = 0., a10 = 0., a11 = 0.;
#pragma unroll 8
  for (int k = 0; k < 64; ++k) {
    double x0 = As[2 * ty][k], x1 = As[2 * ty + 1][k];
    double y0 = Bs[k][2 * tx], y1 = Bs[k][2 * tx + 1];
    a00 = fma(x0, y0, a00); a01 = fma(x0, y1, a01);
    a10 = fma(x1, y0, a10); a11 = fma(x1, y1, a11);
  }
  int r0 = row0 + 2 * ty, c0 = col0 + 2 * tx;
  if (r0 < M) {
    __hip_atomic_fetch_add(&C[(size_t)r0 * 256 + c0], a00, __ATOMIC_RELAXED, __HIP_MEMORY_SCOPE_AGENT);
    __hip_atomic_fetch_add(&C[(size_t)r0 * 256 + c0 + 1], a01, __ATOMIC_RELAXED, __HIP_MEMORY_SCOPE_AGENT);
  }
  if (r0 + 1 < M) {
    __hip_atomic_fetch_add(&C[(size_t)(r0 + 1) * 256 + c0], a10, __ATOMIC_RELAXED, __HIP_MEMORY_SCOPE_AGENT);
    __hip_atomic_fetch_add(&C[(size_t)(r0 + 1) * 256 + c0 + 1], a11, __ATOMIC_RELAXED, __HIP_MEMORY_SCOPE_AGENT);
  }
}

// ---- k_pack: KK fp64 -> packed hi/lo u32 tables (one tiny pass) ----
__global__ __launch_bounds__(256) void k_pack(float* __restrict__ ws) {
  int idx = blockIdx.x * 256 + threadIdx.x;  // 0..172031 (672 blocks)
  const double* KD = (const double*)(ws + WOFF) + KKD64;
  const int kko[3] = {KKOFF0, KKOFF1, KKOFF2};
  int s, local;
  if (idx < 24576) { s = 0; local = idx; }
  else if (idx < 73728) { s = 1; local = idx - 24576; }
  else { s = 2; local = idx - 73728; }
  ((u32*)ws)[kko[s] + local] = pack_hl((float)KD[idx]);
}

// ---- S3 (MFMA split-bf16, global_load_lds 2-phase): Wtil = w x E^T ----
// In-flight data lives in LDS via async global_load_lds (zero VGPR cost).
// Double-buffered 8KB chunks [2 i][32 o][32 x] f32, one barrier per chunk.
// Waves = (il, f): one i-row, one 32-t fragment, full K=256, acc = 1 f32x16.
// Output PACKED (hi|lo u32), layout Wtil2[i>>3][n][i&7], n=x*96+t.
__global__ __launch_bounds__(384, 5) void k_s3(const float* __restrict__ wr,
                                               const float* __restrict__ wi,
                                               float* __restrict__ ws) {
  __shared__ float stage[2][2048];   // 16 KB A staging
  __shared__ u32 pairs[3 * 1056];    // 12.7 KB epilogue pairing
  int bid = blockIdx.x;
  int jidx = bid >> 7;
  int r127 = bid & 127;
  int mb = ((r127 & 7) << 4) | (r127 >> 3);  // XCD-group swizzle (bijective)
  int s = jidx >> 1, p = jidx & 1;
  const float* w = (p ? wi : wr) + (size_t)s * 2097152;
  const u16* ebase = (const u16*)((const u32*)ws + EPOFF);
  const u16* eh = ebase + (size_t)s * 24576;
  const u16* el = ebase + 73728 + (size_t)s * 24576;
  int i0 = mb * 2;
  int tid = threadIdx.x;
  int lane = tid & 63;
  int wid = tid >> 6;
  int il = wid & 1, f = wid >> 1;

  int tcol = lane & 31;          // A row (x) / B col (t within f) / D col
  int og8 = (lane >> 5) << 3;    // k sub-group (which 8 of 16 k)
  const u16* bhp = eh + (size_t)(f * 32 + tcol) * 256 + og8;
  const u16* blp = el + (size_t)(f * 32 + tcol) * 256 + og8;

  bool stager = (wid < 4);
  int sq0 = wid * 2;
  int s_i[2], s_o[2], s_x[2];
#pragma unroll
  for (int j = 0; j < 2; ++j) {
    int qq = sq0 + j;
    s_i[j] = qq >> 2;
    s_o[j] = (qq & 3) * 8 + (lane >> 3);
    s_x[j] = (lane & 7) * 4;
  }

  f32x16 acc;
#pragma unroll
  for (int r = 0; r < 16; ++r) acc[r] = 0.f;

  if (stager) {
#pragma unroll
    for (int j = 0; j < 2; ++j) {
      const float* g = w + (((size_t)(i0 + s_i[j]) * 256 + s_o[j]) << 5) + s_x[j];
      gload_lds16(g, &stage[0][(sq0 + j) * 256]);
    }
  }
  __syncthreads();

#pragma unroll 2
  for (int c = 0; c < 8; ++c) {
    int buf = c & 1;
    if (c < 7 && stager) {
      int kon = (c + 1) * 32;
#pragma unroll
      for (int j = 0; j < 2; ++j) {
        const float* g = w + (((size_t)(i0 + s_i[j]) * 256 + kon + s_o[j]) << 5) + s_x[j];
        gload_lds16(g, &stage[buf ^ 1][(sq0 + j) * 256]);
      }
    }
    int ko = c * 32;
#pragma unroll
    for (int ks = 0; ks < 2; ++ks) {
      int ob = ks * 16 + og8;
      float fa[8];
#pragma unroll
      for (int j = 0; j < 8; ++j)
        fa[j] = stage[buf][il * 1024 + (ob + j) * 32 + tcol];
      bf16x8 ah, al;
#pragma unroll
      for (int j = 0; j < 8; ++j) {
        __bf16 h = (__bf16)fa[j];
        ah[j] = h;
        al[j] = (__bf16)(fa[j] - (float)h);
      }
      bf16x8 bh = *(const bf16x8*)(bhp + ko + ks * 16);
      bf16x8 bl = *(const bf16x8*)(blp + ko + ks * 16);
      acc = __builtin_amdgcn_mfma_f32_32x32x16_bf16(ah, bh, acc, 0, 0, 0);
      acc = __builtin_amdgcn_mfma_f32_32x32x16_bf16(ah, bl, acc, 0, 0, 0);
      acc = __builtin_amdgcn_mfma_f32_32x32x16_bf16(al, bh, acc, 0, 0, 0);
    }
    __syncthreads();
  }

  // pack own values; pair il=0/il=1 through LDS; il=1 stores uint2
  int x0 = (lane >> 5) << 2;
  u32 mine[16];
#pragma unroll
  for (int r = 0; r < 16; ++r) mine[r] = pack_hl(acc[r]);
  if (il == 0) {
#pragma unroll
    for (int r = 0; r < 16; ++r) {
      int row = x0 + (r & 3) + ((r >> 2) << 3);
      pairs[f * 1056 + row * 33 + tcol] = mine[r];
    }
  }
  __syncthreads();
  if (il == 1) {
    u32* W2 = (u32*)(ws + WOFF) + (size_t)jidx * 786432 +
              (size_t)(mb >> 2) * 24576 + ((mb & 3) << 1);
#pragma unroll
    for (int r = 0; r < 16; ++r) {
      int row = x0 + (r & 3) + ((r >> 2) << 3);
      uint2 st;
      st.x = pairs[f * 1056 + row * 33 + tcol];
      st.y = mine[r];
      *(uint2*)(W2 + (size_t)(row * 96 + f * 32 + tcol) * 8) = st;
    }
  }
}

// ---- S4 (MFMA split-bf16, zero-LDS): R[d,n] = sum_i KK[d,i]*Wtil[i,n] ----
__global__ __launch_bounds__(256) void k_s4(float* __restrict__ ws) {
  int bid = blockIdx.x;
  const int cums[6] = {0, 36, 72, 144, 216, 360};  // tiles: (T/32)*12 per (s,p)
  int jidx = 0;
#pragma unroll
  for (int q = 1; q < 6; ++q) if (bid >= cums[q]) jidx = q;
  int local = bid - cums[jidx];
  int s = jidx >> 1, p = jidx & 1;
  const int Ts[3] = {96, 192, 384};
  const int KKo[3] = {KKOFF0, KKOFF1, KKOFF2};
  const int Ro[3] = {R0OFF, R1OFF, R2OFF};
  int T = Ts[s];
  int td = local / 12, tn = local % 12;
  int d0 = td * 32;
  int tid = threadIdx.x;
  int lane = tid & 63, wid = tid >> 6;
  int n0 = tn * 256 + wid * 64;
  int l31 = lane & 31, kg = lane >> 5;
  const u32* Ap = (const u32*)ws + KKo[s] + (size_t)(d0 + l31) * 256 + kg * 8;
  const u32* Bp = (const u32*)ws + WOFF + (size_t)jidx * 786432 + (size_t)kg * 24576;
  const u32* b0p = Bp + (size_t)(n0 + l31) * 8;
  const u32* b1p = Bp + (size_t)(n0 + 32 + l31) * 8;
  float* C = ws + Ro[s] + (size_t)p * T * 3072;

  f32x16 acc0, acc1;
#pragma unroll
  for (int r = 0; r < 16; ++r) { acc0[r] = 0.f; acc1[r] = 0.f; }

#pragma unroll 2
  for (int ks = 0; ks < 16; ++ks) {
    uint4 a0 = *(const uint4*)(Ap + ks * 16);
    uint4 a1 = *(const uint4*)(Ap + ks * 16 + 4);
    size_t bo = (size_t)ks * 49152;
    uint4 x0 = *(const uint4*)(b0p + bo);
    uint4 x1 = *(const uint4*)(b0p + bo + 4);
    uint4 y0 = *(const uint4*)(b1p + bo);
    uint4 y1 = *(const uint4*)(b1p + bo + 4);
    u32 ap[8] = {a0.x, a0.y, a0.z, a0.w, a1.x, a1.y, a1.z, a1.w};
    bf16x8 ah, al;
    unpk8(ap, ah, al);
    {
      u32 bp[8] = {x0.x, x0.y, x0.z, x0.w, x1.x, x1.y, x1.z, x1.w};
      bf16x8 bh, bl;
      unpk8(bp, bh, bl);
      acc0 = __builtin_amdgcn_mfma_f32_32x32x16_bf16(ah, bh, acc0, 0, 0, 0);
      acc0 = __builtin_amdgcn_mfma_f32_32x32x16_bf16(ah, bl, acc0, 0, 0, 0);
      acc0 = __builtin_amdgcn_mfma_f32_32x32x16_bf16(al, bh, acc0, 0, 0, 0);
      acc0 = __builtin_amdgcn_mfma_f32_32x32x16_bf16(al, bl, acc0, 0, 0, 0);
    }
    {
      u32 bp[8] = {y0.x, y0.y, y0.z, y0.w, y1.x, y1.y, y1.z, y1.w};
      bf16x8 bh, bl;
      unpk8(bp, bh, bl);
      acc1 = __builtin_amdgcn_mfma_f32_32x32x16_bf16(ah, bh, acc1, 0, 0, 0);
      acc1 = __builtin_amdgcn_mfma_f32_32x32x16_bf16(ah, bl, acc1, 0, 0, 0);
      acc1 = __builtin_amdgcn_mfma_f32_32x32x16_bf16(al, bh, acc1, 0, 0, 0);
      acc1 = __builtin_amdgcn_mfma_f32_32x32x16_bf16(al, bl, acc1, 0, 0, 0);
    }
  }

  int crow = kg << 2;
#pragma unroll
  for (int r = 0; r < 16; ++r) {
    int row = d0 + crow + (r & 3) + ((r >> 2) << 3);
    C[(size_t)row * 3072 + n0 + l31] = acc0[r];
    C[(size_t)row * 3072 + n0 + 32 + l31] = acc1[r];
  }
}

// ---- S5a: prefix-DFT over d + irfft phase, accumulate w_s * val into Htot ----
__global__ __launch_bounds__(192) void k_s5a(const float* __restrict__ mlpw, float* __restrict__ ws) {
  int bid = blockIdx.x;
  int s = bid >> 7;
  int rem = bid & 127;
  int x = rem >> 2;
  int tq = rem & 3;
  const int Ts[3] = {96, 192, 384};
  const int Ro[3] = {R0OFF, R1OFF, R2OFF};
  const int lpbase[3] = {288, 192, 0};
  int T = Ts[s];
  int Lc = T >> 3;
  __shared__ float cs[384][2];
  __shared__ float Lsr[8][24], Lsi[8][24];
  int tid = threadIdx.x;
  for (int e = tid; e < T; e += 192) {
    float th = 6.283185307179586f * (float)e / (float)T;
    cs[e][0] = cosf(th);
    cs[e][1] = sinf(th);
  }
  int c = tid / 24, tl = tid % 24;
  int t = tq * 24 + tl;
  const float* Rre = ws + Ro[s] + (size_t)x * 96 + t;
  const float* Rim = Rre + (size_t)T * 3072;
  float* Htot = ws + HTOTOFF;
  float wsc = mlpw[s];
  __syncthreads();
  int d0 = c * Lc;
  float zr = 0.f, zi = 0.f;
  for (int d = d0; d < d0 + Lc; ++d) {
    float rr = Rre[(size_t)d * 3072];
    float ri = Rim[(size_t)d * 3072];
    int e1 = (x * d) % T;
    float c1 = cs[e1][0], s1 = cs[e1][1];
    zr += c1 * rr + s1 * ri;
    zi += c1 * ri - s1 * rr;
  }
  Lsr[c][tl] = zr; Lsi[c][tl] = zi;
  __syncthreads();
  if (c == 0) {
    float pr = 0.f, pi = 0.f;
#pragma unroll
    for (int cc = 0; cc < 8; ++cc) {
      float lr = Lsr[cc][tl], li = Lsi[cc][tl];
      Lsr[cc][tl] = pr; Lsi[cc][tl] = pi;
      pr += lr; pi += li;
    }
  }
  __syncthreads();
  zr = Lsr[c][tl]; zi = Lsi[c][tl];
  float sc = (((x == 0) ? 1.f : 2.f) / (float)T) * wsc;
  for (int d = d0; d < d0 + Lc; ++d) {
    float rr = Rre[(size_t)d * 3072];
    float ri = Rim[(size_t)d * 3072];
    int e1 = (x * d) % T;
    float c1 = cs[e1][0], s1 = cs[e1][1];
    zr += c1 * rr + s1 * ri;
    zi += c1 * ri - s1 * rr;
    int k = T - 1 - d;
    int e2 = (x * (95 - k)) % T;
    if (e2 < 0) e2 += T;
    float c2 = cs[e2][0], s2 = cs[e2][1];
    atomicAdd(Htot + (size_t)(lpbase[s] + k) * 96 + t, sc * (c2 * zr - s2 * zi));
  }
}

// ---- S6: out[b,t,j] = sum_l x*Htot + mean*(1-S[t]) + std*mlp_b ----
__global__ __launch_bounds__(256) void k_s6(const float* __restrict__ xin, const float* __restrict__ mlpb_p,
                                            const float* __restrict__ ws, float* __restrict__ out) {
  int b = blockIdx.x >> 2, tq = blockIdx.x & 3;
  int tid = threadIdx.x;
  int j = tid & 63, tsub = tid >> 6;
  __shared__ float Ht[384 * 24];
  for (int idx = tid; idx < 384 * 24; idx += 256) {
    int lp = idx / 24, c = idx % 24;
    Ht[idx] = ws[HTOTOFF + lp * 96 + tq * 24 + c];
  }
  float ssum = 0.f, sq = 0.f;
#pragma unroll
  for (int p = 0; p < 12; ++p) {
    const float* src = ws + STATSP + (((size_t)b * 12 + p) * 64 + j) * 2;
    ssum += src[0]; sq += src[1];
  }
  float mn = ssum * (1.f / 720.f);
  float var = sq * (1.f / 720.f) - mn * mn;
  float sd = sqrtf(var + 1e-5f);
  __syncthreads();
  float mlpb = mlpb_p[0];
  float acc[6] = {0.f, 0.f, 0.f, 0.f, 0.f, 0.f};
  float accS[6] = {0.f, 0.f, 0.f, 0.f, 0.f, 0.f};
  const float* xp = xin + ((size_t)b * 720 + 336) * 64 + j;
  for (int lp = 0; lp < 384; ++lp) {
    float xv = xp[(size_t)lp * 64];
    const float* hr = &Ht[lp * 24 + tsub * 6];
    float2 h01 = *(const float2*)&hr[0];
    float2 h23 = *(const float2*)&hr[2];
    float2 h45 = *(const float2*)&hr[4];
    float hh[6] = {h01.x, h01.y, h23.x, h23.y, h45.x, h45.y};
#pragma unroll
    for (int u = 0; u < 6; ++u) {
      acc[u] += xv * hh[u];
      accS[u] += hh[u];
    }
  }
#pragma unroll
  for (int u = 0; u < 6; ++u) {
    int t = tq * 24 + tsub * 6 + u;
    float val = acc[u] + mn * (1.f - accS[u]) + sd * mlpb;
    out[((size_t)b * 96 + t) * 64 + j] = val;
  }
}

extern "C" void kernel_launch(void* const* d_in, const int* in_sizes, int n_in,
                              void* d_out, int out_size, void* d_ws, size_t ws_size,
                              hipStream_t stream) {
  const float* x  = (const float*)d_in[0];
  const float* wr = (const float*)d_in[1];
  const float* wi = (const float*)d_in[2];
  const float* mw = (const float*)d_in[3];
  const float* mb = (const float*)d_in[4];
  const float* Ab = (const float*)d_in[5];
  const float* Bb = (const float*)d_in[6];
  const float* ev = (const float*)d_in[7];
  float* wsf = (float*)d_ws;
  float* out = (float*)d_out;

  k_pre<<<1635, 256, 0, stream>>>(Ab, Bb, x, ev, wsf);

  const double* AD = (const double*)(wsf + WOFF) + AD64;
  double* PD = (double*)(wsf + WOFF) + PD64;
  double* KD = (double*)(wsf + WOFF) + KKD64;
  static const int Ts[3] = {96, 192, 384};
  static const int rowoff[3] = {0, 24576, 73728};

  // Doubling: round r extends KK rows [n, min(2n,T)) = KK[0,n) * P_n^T and
  // squares P_n -> P_2n (triple-buffered; free buf pre-zeroed for round r+1).
  int have[3] = {1, 1, 1};
  for (int r = 0; r <= 8; ++r) {
    CJobs jb;
    jb.njobs = 0;
    int tiles = 0;
    for (int s = 0; s < 3; ++s) {
      int T = Ts[s];
      if (have[s] >= T) continue;
      const double* Pn = (r == 0) ? (AD + (size_t)s * 65536)
                                  : (PD + (size_t)(s * 3 + (r - 1) % 3) * 65536);
      int M = ((2 * have[s] < T) ? 2 * have[s] : T) - have[s];
      int q = jb.njobs++;
      jb.A[q] = KD + rowoff[s]; jb.B[q] = Pn;
      jb.C[q] = KD + rowoff[s] + (size_t)have[s] * 256;
      jb.M[q] = M; jb.transB[q] = 1; jb.tile0[q] = tiles;
      tiles += ((M + 31) / 32) * 32;
      if (2 * have[s] < T) {
        q = jb.njobs++;
        jb.A[q] = Pn; jb.B[q] = Pn;
        jb.C[q] = PD + (size_t)(s * 3 + r % 3) * 65536;
        jb.M[q] = 256; jb.transB[q] = 0; jb.tile0[q] = tiles;
        tiles += 256;
        if (4 * have[s] < T) {  // will square next round: zero its dst now
          q = jb.njobs++;
          jb.A[q] = nullptr; jb.B[q] = nullptr;
          jb.C[q] = PD + (size_t)(s * 3 + (r + 1) % 3) * 65536;
          jb.M[q] = 0; jb.transB[q] = 2; jb.tile0[q] = tiles;
          tiles += 64;
        }
      }
      have[s] = (2 * have[s] < T) ? 2 * have[s] : T;
    }
    if (jb.njobs) k_chain<<<tiles, 256, 0, stream>>>(jb);
  }

  k_pack<<<672, 256, 0, stream>>>(wsf);
  k_s3<<<768, 384, 0, stream>>>(wr, wi, wsf);
  k_s4<<<504, 256, 0, stream>>>(wsf);
  k_s5a<<<384, 192, 0, stream>>>(mw, wsf);
  k_s6<<<64, 256, 0, stream>>>(x, mb, wsf, out);
}

// Round 7
// 316.733 us; speedup vs baseline: 1.2129x; 1.0433x over previous
//
#include <hip/hip_runtime.h>

typedef unsigned short u16;
typedef unsigned int u32;

typedef __bf16 bf16x8 __attribute__((ext_vector_type(8)));
typedef unsigned short ushort8 __attribute__((ext_vector_type(8)));
typedef float f32x16 __attribute__((ext_vector_type(16)));

// workspace offsets (in floats)
#define STATSP 2048     // 16*12*64*2 = 24576 floats of stats partials
#define EPOFF 32768     // E split tables: [hi: 73728 u16][lo: 73728 u16]
#define KKOFF0 591872
#define KKOFF1 616448
#define KKOFF2 665600
#define WOFF 763904
#define R0OFF 5482496
#define R1OFF 6072320
#define R2OFF 7251968
#define SCROFF 9611264  // s5 chunk partials: [3][32][16][96][2] f32 = 294912 (free gap)
#define HTOTOFF 11675648
// total = 11712512 floats = ~46.9 MB
// fp64 chain scratch lives INSIDE the Wtil region [WOFF, R0OFF); it is fully
// consumed (k_pack) before k_s3 overwrites Wtil. Offsets in doubles relative
// to (double*)(ws + WOFF):
#define AD64 0        // 3*65536 doubles  (Ad fp64, per scale)
#define PD64 196608   // 9*65536 doubles  (P TRIPLE-buffer: (s*3+b)*65536)
#define KKD64 786432  // 672*256 doubles  (KK rows fp64: s0 96, s1 192, s2 384)
// KK (packed hi/lo u32) lives at KKOFF*; Wtil2 (packed u32, layout
// [i>>3][n][i&7], n = x*96+t) lives at WOFF + jidx*786432 (u32 view).

// float -> packed u32: low16 = bf16 RNE of a, high16 = bf16 of residual
__device__ __forceinline__ u32 pack_hl(float a) {
  u32 bits = __builtin_bit_cast(u32, a);
  u32 hi = (bits + 0x7fffu + ((bits >> 16) & 1u)) >> 16;
  float hif = __builtin_bit_cast(float, hi << 16);
  float r = a - hif;
  u32 lo = __builtin_bit_cast(u32, r) >> 16;
  return hi | (lo << 16);
}

__device__ __forceinline__ void unpk8(const u32* p, bf16x8& h, bf16x8& l) {
  ushort8 hu, lu;
#pragma unroll
  for (int j = 0; j < 8; ++j) {
    u32 v = p[j];
    hu[j] = (unsigned short)(v & 0xffffu);
    lu[j] = (unsigned short)(v >> 16);
  }
  h = __builtin_bit_cast(bf16x8, hu);
  l = __builtin_bit_cast(bf16x8, lu);
}

// async global->LDS, 16B per lane; LDS dest is wave-uniform base + lane*16
__device__ __forceinline__ void gload_lds16(const float* g, float* l) {
  __builtin_amdgcn_global_load_lds(
      (const __attribute__((address_space(1))) void*)g,
      (__attribute__((address_space(3))) void*)l, 16, 0, 0);
}

// ---- k_pre: A->fp64, seed KK row0, stats1, zero Htot/PD0/KD, pack E ----
__global__ __launch_bounds__(256) void k_pre(const float* __restrict__ Ab,
                                             const float* __restrict__ Bb,
                                             const float* __restrict__ xin,
                                             const float* __restrict__ ev,
                                             float* __restrict__ ws) {
  __shared__ float rs[4][64], rq[4][64];
  int blk = blockIdx.x, tid = threadIdx.x;
  if (blk < 771) {
    double* dws = (double*)(ws + WOFF);
    int idx = blk * 256 + tid;
    if (idx < 196608) {
      dws[AD64 + idx] = (double)Ab[idx];
    } else {
      int g = idx - 196608;  // 0..767 (grid sized exactly)
      const int rowoff[3] = {0, 24576, 73728};
      int s = g >> 8, i = g & 255;
      dws[KKD64 + rowoff[s] + i] = (double)Bb[g];
    }
  } else if (blk < 963) {
    int b2 = blk - 771;  // 0..191
    int b = b2 / 12, part = b2 % 12;
    int j = tid & 63, g = tid >> 6;
    const float* xp = xin + ((size_t)b * 720 + part * 60 + g) * 64 + j;
    float sum = 0.f, ss = 0.f;
#pragma unroll
    for (int i = 0; i < 15; ++i) {
      float v = xp[(size_t)i * 256];
      sum += v; ss += v * v;
    }
    rs[g][j] = sum; rq[g][j] = ss;
    __syncthreads();
    if (g == 0) {
      float s = rs[0][j] + rs[1][j] + rs[2][j] + rs[3][j];
      float q = rq[0][j] + rq[1][j] + rq[2][j] + rq[3][j];
      float* dst = ws + STATSP + ((size_t)b2 * 64 + j) * 2;
      dst[0] = s; dst[1] = q;
    }
  } else if (blk < 987) {
    int idx = (blk - 963) * 256 + tid;
    for (; idx < 36864; idx += 24 * 256) ws[HTOTOFF + idx] = 0.f;
  } else if (blk < 1275) {
    // E pack: ev [3][96][256] -> SPLIT u16 tables: hi[idx], lo[73728+idx]
    int idx = (blk - 987) * 256 + tid;  // 0..73727 (288 blocks exactly)
    u32 ph = pack_hl(ev[idx]);
    u16* eb = (u16*)((u32*)ws + EPOFF);
    eb[idx] = (u16)(ph & 0xffffu);
    eb[73728 + idx] = (u16)(ph >> 16);
  } else if (blk < 1467) {
    // zero PD buf0 for each scale (dst of chain round 0)
    int g0 = ((blk - 1275) * 256 + tid) * 4;  // 0..196607, 192 blocks
    int s = g0 >> 16, off = g0 & 65535;
    double* dst = (double*)(ws + WOFF) + PD64 + (size_t)(s * 3) * 65536 + off;
    dst[0] = 0.; dst[1] = 0.; dst[2] = 0.; dst[3] = 0.;
  } else {
    // zero KD fp64 rows EXCEPT each scale's seeded row 0
    int g0 = ((blk - 1467) * 256 + tid) * 4;  // 0..172031, 168 blocks
    int local = (g0 < 24576) ? g0 : (g0 < 73728 ? g0 - 24576 : g0 - 73728);
    if (local >= 256) {
      double* dst = (double*)(ws + WOFF) + KKD64 + g0;
      dst[0] = 0.; dst[1] = 0.; dst[2] = 0.; dst[3] = 0.;
    }
  }
}

// ---- fp64 chain kernel: lean 32x32 tiles x 4-way K-split, atomic combine ----
struct CJobs {
  const double* A[12]; const double* B[12]; double* C[12];
  int M[12]; int transB[12]; int tile0[12];
  int njobs;
};

__global__ __launch_bounds__(256) void k_chain(CJobs jb) {
  int bid = blockIdx.x;
  int j = 0;
  for (int q = 1; q < jb.njobs; ++q) if (bid >= jb.tile0[q]) j = q;
  int local = bid - jb.tile0[j];
  int tB = jb.transB[j];
  int tid = threadIdx.x;
  if (tB == 2) {  // zero job: 64 tiles x 1024 doubles
    double* Z = jb.C[j] + (size_t)local * 1024 + tid * 4;
    Z[0] = 0.; Z[1] = 0.; Z[2] = 0.; Z[3] = 0.;
    return;
  }
  int M = jb.M[j];
  const double* A = jb.A[j];
  const double* Bm = jb.B[j];
  double* C = jb.C[j];
  int kq = local & 3, tn = (local >> 2) & 7, tm = local >> 5;
  int row0 = tm * 32, col0 = tn * 32, k0 = kq * 64;
  __shared__ double As[32][65];
  __shared__ double Bs[64][33];
  {
    int r = tid >> 3, k8 = (tid & 7) << 3;
    if (row0 + r < M) {
      const double* src = A + (size_t)(row0 + r) * 256 + k0 + k8;
#pragma unroll
      for (int u = 0; u < 8; ++u) As[r][k8 + u] = src[u];
    } else {
#pragma unroll
      for (int u = 0; u < 8; ++u) As[r][k8 + u] = 0.0;
    }
  }
  if (tB == 0) {
    int k = tid >> 2, c8 = (tid & 3) << 3;
    const double* src = Bm + (size_t)(k0 + k) * 256 + col0 + c8;
#pragma unroll
    for (int u = 0; u < 8; ++u) Bs[k][c8 + u] = src[u];
  } else {
    int c = tid >> 3, k8 = (tid & 7) << 3;
    const double* src = Bm + (size_t)(col0 + c) * 256 + k0 + k8;
#pragma unroll
    for (int u = 0; u < 8; ++u) Bs[k8 + u][c] = src[u];
  }
  __syncthreads();
  int ty = tid >> 4, tx = tid & 15;
  double a00 = 0., a01 = 0., a10 = 0., a11 = 0.;
#pragma unroll 8
  for (int k = 0; k < 64; ++k) {
    double x0 = As[2 * ty][k], x1 = As[2 * ty + 1][k];
    double y0 = Bs[k][2 * tx], y1 = Bs[k][2 * tx + 1];
    a00 = fma(x0, y0, a00); a01 = fma(x0, y1, a01);
    a10 = fma(x1, y0, a10); a11 = fma(x1, y1, a11);
  }
  int r0 = row0 + 2 * ty, c0 = col0 + 2 * tx;
  if (r0 < M) {
    __hip_atomic_fetch_add(&C[(size_t)r0 * 256 + c0], a00, __ATOMIC_RELAXED, __HIP_MEMORY_SCOPE_AGENT);
    __hip_atomic_fetch_add(&C[(size_t)r0 * 256 + c0 + 1], a01, __ATOMIC_RELAXED, __HIP_MEMORY_SCOPE_AGENT);
  }
  if (r0 + 1 < M) {
    __hip_atomic_fetch_add(&C[(size_t)(r0 + 1) * 256 + c0], a10, __ATOMIC_RELAXED, __HIP_MEMORY_SCOPE_AGENT);
    __hip_atomic_fetch_add(&C[(size_t)(r0 + 1) * 256 + c0 + 1], a11, __ATOMIC_RELAXED, __HIP_MEMORY_SCOPE_AGENT);
  }
}

// ---- k_pack: KK fp64 -> packed hi/lo u32 tables (one tiny pass) ----
__global__ __launch_bounds__(256) void k_pack(float* __restrict__ ws) {
  int idx = blockIdx.x * 256 + threadIdx.x;  // 0..172031 (672 blocks)
  const double* KD = (const double*)(ws + WOFF) + KKD64;
  const int kko[3] = {KKOFF0, KKOFF1, KKOFF2};
  int s, local;
  if (idx < 24576) { s = 0; local = idx; }
  else if (idx < 73728) { s = 1; local = idx - 24576; }
  else { s = 2; local = idx - 73728; }
  ((u32*)ws)[kko[s] + local] = pack_hl((float)KD[idx]);
}

// ---- S3 (MFMA split-bf16, global_load_lds 2-phase): Wtil = w x E^T ----
__global__ __launch_bounds__(384, 5) void k_s3(const float* __restrict__ wr,
                                               const float* __restrict__ wi,
                                               float* __restrict__ ws) {
  __shared__ float stage[2][2048];   // 16 KB A staging
  __shared__ u32 pairs[3 * 1056];    // 12.7 KB epilogue pairing
  int bid = blockIdx.x;
  int jidx = bid >> 7;
  int r127 = bid & 127;
  int mb = ((r127 & 7) << 4) | (r127 >> 3);  // XCD-group swizzle (bijective)
  int s = jidx >> 1, p = jidx & 1;
  const float* w = (p ? wi : wr) + (size_t)s * 2097152;
  const u16* ebase = (const u16*)((const u32*)ws + EPOFF);
  const u16* eh = ebase + (size_t)s * 24576;
  const u16* el = ebase + 73728 + (size_t)s * 24576;
  int i0 = mb * 2;
  int tid = threadIdx.x;
  int lane = tid & 63;
  int wid = tid >> 6;
  int il = wid & 1, f = wid >> 1;

  int tcol = lane & 31;
  int og8 = (lane >> 5) << 3;
  const u16* bhp = eh + (size_t)(f * 32 + tcol) * 256 + og8;
  const u16* blp = el + (size_t)(f * 32 + tcol) * 256 + og8;

  bool stager = (wid < 4);
  int sq0 = wid * 2;
  int s_i[2], s_o[2], s_x[2];
#pragma unroll
  for (int j = 0; j < 2; ++j) {
    int qq = sq0 + j;
    s_i[j] = qq >> 2;
    s_o[j] = (qq & 3) * 8 + (lane >> 3);
    s_x[j] = (lane & 7) * 4;
  }

  f32x16 acc;
#pragma unroll
  for (int r = 0; r < 16; ++r) acc[r] = 0.f;

  if (stager) {
#pragma unroll
    for (int j = 0; j < 2; ++j) {
      const float* g = w + (((size_t)(i0 + s_i[j]) * 256 + s_o[j]) << 5) + s_x[j];
      gload_lds16(g, &stage[0][(sq0 + j) * 256]);
    }
  }
  __syncthreads();

#pragma unroll 2
  for (int c = 0; c < 8; ++c) {
    int buf = c & 1;
    if (c < 7 && stager) {
      int kon = (c + 1) * 32;
#pragma unroll
      for (int j = 0; j < 2; ++j) {
        const float* g = w + (((size_t)(i0 + s_i[j]) * 256 + kon + s_o[j]) << 5) + s_x[j];
        gload_lds16(g, &stage[buf ^ 1][(sq0 + j) * 256]);
      }
    }
    int ko = c * 32;
#pragma unroll
    for (int ks = 0; ks < 2; ++ks) {
      int ob = ks * 16 + og8;
      float fa[8];
#pragma unroll
      for (int j = 0; j < 8; ++j)
        fa[j] = stage[buf][il * 1024 + (ob + j) * 32 + tcol];
      bf16x8 ah, al;
#pragma unroll
      for (int j = 0; j < 8; ++j) {
        __bf16 h = (__bf16)fa[j];
        ah[j] = h;
        al[j] = (__bf16)(fa[j] - (float)h);
      }
      bf16x8 bh = *(const bf16x8*)(bhp + ko + ks * 16);
      bf16x8 bl = *(const bf16x8*)(blp + ko + ks * 16);
      acc = __builtin_amdgcn_mfma_f32_32x32x16_bf16(ah, bh, acc, 0, 0, 0);
      acc = __builtin_amdgcn_mfma_f32_32x32x16_bf16(ah, bl, acc, 0, 0, 0);
      acc = __builtin_amdgcn_mfma_f32_32x32x16_bf16(al, bh, acc, 0, 0, 0);
    }
    __syncthreads();
  }

  // pack own values; pair il=0/il=1 through LDS; il=1 stores uint2
  int x0 = (lane >> 5) << 2;
  u32 mine[16];
#pragma unroll
  for (int r = 0; r < 16; ++r) mine[r] = pack_hl(acc[r]);
  if (il == 0) {
#pragma unroll
    for (int r = 0; r < 16; ++r) {
      int row = x0 + (r & 3) + ((r >> 2) << 3);
      pairs[f * 1056 + row * 33 + tcol] = mine[r];
    }
  }
  __syncthreads();
  if (il == 1) {
    u32* W2 = (u32*)(ws + WOFF) + (size_t)jidx * 786432 +
              (size_t)(mb >> 2) * 24576 + ((mb & 3) << 1);
#pragma unroll
    for (int r = 0; r < 16; ++r) {
      int row = x0 + (r & 3) + ((r >> 2) << 3);
      uint2 st;
      st.x = pairs[f * 1056 + row * 33 + tcol];
      st.y = mine[r];
      *(uint2*)(W2 + (size_t)(row * 96 + f * 32 + tcol) * 8) = st;
    }
  }
}

// ---- S4 (MFMA split-bf16, zero-LDS): R[d,n] = sum_i KK[d,i]*Wtil[i,n] ----
__global__ __launch_bounds__(256) void k_s4(float* __restrict__ ws) {
  int bid = blockIdx.x;
  const int cums[6] = {0, 36, 72, 144, 216, 360};  // tiles: (T/32)*12 per (s,p)
  int jidx = 0;
#pragma unroll
  for (int q = 1; q < 6; ++q) if (bid >= cums[q]) jidx = q;
  int local = bid - cums[jidx];
  int s = jidx >> 1, p = jidx & 1;
  const int Ts[3] = {96, 192, 384};
  const int KKo[3] = {KKOFF0, KKOFF1, KKOFF2};
  const int Ro[3] = {R0OFF, R1OFF, R2OFF};
  int T = Ts[s];
  int td = local / 12, tn = local % 12;
  int d0 = td * 32;
  int tid = threadIdx.x;
  int lane = tid & 63, wid = tid >> 6;
  int n0 = tn * 256 + wid * 64;
  int l31 = lane & 31, kg = lane >> 5;
  const u32* Ap = (const u32*)ws + KKo[s] + (size_t)(d0 + l31) * 256 + kg * 8;
  const u32* Bp = (const u32*)ws + WOFF + (size_t)jidx * 786432 + (size_t)kg * 24576;
  const u32* b0p = Bp + (size_t)(n0 + l31) * 8;
  const u32* b1p = Bp + (size_t)(n0 + 32 + l31) * 8;
  float* C = ws + Ro[s] + (size_t)p * T * 3072;

  f32x16 acc0, acc1;
#pragma unroll
  for (int r = 0; r < 16; ++r) { acc0[r] = 0.f; acc1[r] = 0.f; }

#pragma unroll 2
  for (int ks = 0; ks < 16; ++ks) {
    uint4 a0 = *(const uint4*)(Ap + ks * 16);
    uint4 a1 = *(const uint4*)(Ap + ks * 16 + 4);
    size_t bo = (size_t)ks * 49152;
    uint4 x0 = *(const uint4*)(b0p + bo);
    uint4 x1 = *(const uint4*)(b0p + bo + 4);
    uint4 y0 = *(const uint4*)(b1p + bo);
    uint4 y1 = *(const uint4*)(b1p + bo + 4);
    u32 ap[8] = {a0.x, a0.y, a0.z, a0.w, a1.x, a1.y, a1.z, a1.w};
    bf16x8 ah, al;
    unpk8(ap, ah, al);
    {
      u32 bp[8] = {x0.x, x0.y, x0.z, x0.w, x1.x, x1.y, x1.z, x1.w};
      bf16x8 bh, bl;
      unpk8(bp, bh, bl);
      acc0 = __builtin_amdgcn_mfma_f32_32x32x16_bf16(ah, bh, acc0, 0, 0, 0);
      acc0 = __builtin_amdgcn_mfma_f32_32x32x16_bf16(ah, bl, acc0, 0, 0, 0);
      acc0 = __builtin_amdgcn_mfma_f32_32x32x16_bf16(al, bh, acc0, 0, 0, 0);
      acc0 = __builtin_amdgcn_mfma_f32_32x32x16_bf16(al, bl, acc0, 0, 0, 0);
    }
    {
      u32 bp[8] = {y0.x, y0.y, y0.z, y0.w, y1.x, y1.y, y1.z, y1.w};
      bf16x8 bh, bl;
      unpk8(bp, bh, bl);
      acc1 = __builtin_amdgcn_mfma_f32_32x32x16_bf16(ah, bh, acc1, 0, 0, 0);
      acc1 = __builtin_amdgcn_mfma_f32_32x32x16_bf16(ah, bl, acc1, 0, 0, 0);
      acc1 = __builtin_amdgcn_mfma_f32_32x32x16_bf16(al, bh, acc1, 0, 0, 0);
      acc1 = __builtin_amdgcn_mfma_f32_32x32x16_bf16(al, bl, acc1, 0, 0, 0);
    }
  }

  int crow = kg << 2;
#pragma unroll
  for (int r = 0; r < 16; ++r) {
    int row = d0 + crow + (r & 3) + ((r >> 2) << 3);
    C[(size_t)row * 3072 + n0 + l31] = acc0[r];
    C[(size_t)row * 3072 + n0 + 32 + l31] = acc1[r];
  }
}

// ---- S5 (two-phase decoupled prefix-DFT) ----
// Old k_s5a was a latency wall: VGPR=16 (no ILP), 1.5 blocks/CU (no TLP),
// per-thread serial chain of up to 96 strided loads. Now 16 chunks,
// 768 blocks x 192 thr (2 chunks/block), fully-unrolled template bodies so
// all of a chunk's loads issue together; launch_bounds(192,2) funds them.
// k_s5p: per-chunk partial DFT sums -> scratch. k_s5f: prefix from scratch
// + irfft accumulate pass (same math/order as before per chunk).

template <int LC, int T>
__device__ __forceinline__ void s5_partial(const float* __restrict__ Rre,
                                           const float* __restrict__ Rim,
                                           const float (*cs)[2], int x, int d0,
                                           float& zr, float& zi) {
#pragma unroll
  for (int u = 0; u < LC; ++u) {
    int d = d0 + u;
    float rr = Rre[(size_t)d * 3072];
    float ri = Rim[(size_t)d * 3072];
    int e1 = (x * d) % T;
    float c1 = cs[e1][0], s1 = cs[e1][1];
    zr += c1 * rr + s1 * ri;
    zi += c1 * ri - s1 * rr;
  }
}

template <int LC, int T>
__device__ __forceinline__ void s5_final(const float* __restrict__ Rre,
                                         const float* __restrict__ Rim,
                                         const float (*cs)[2], int x, int d0,
                                         float zr, float zi, float sc,
                                         float* __restrict__ Hdst, int t) {
#pragma unroll
  for (int u = 0; u < LC; ++u) {
    int d = d0 + u;
    float rr = Rre[(size_t)d * 3072];
    float ri = Rim[(size_t)d * 3072];
    int e1 = (x * d) % T;
    float c1 = cs[e1][0], s1 = cs[e1][1];
    zr += c1 * rr + s1 * ri;
    zi += c1 * ri - s1 * rr;
    int k = T - 1 - d;
    int e2 = (x * (95 - k)) % T;
    if (e2 < 0) e2 += T;
    float c2 = cs[e2][0], s2 = cs[e2][1];
    atomicAdd(Hdst + (size_t)k * 96 + t, sc * (c2 * zr - s2 * zi));
  }
}

__global__ __launch_bounds__(192, 2) void k_s5p(float* __restrict__ ws) {
  int bid = blockIdx.x;                 // 768 = 3 s x 32 x x 8 cpair
  int s = bid >> 8;                     // 256 per s
  int rem = bid & 255;
  int x = rem >> 3;
  int cpair = rem & 7;
  const int Ts[3] = {96, 192, 384};
  const int Ro[3] = {R0OFF, R1OFF, R2OFF};
  int T = Ts[s];
  __shared__ float cs[384][2];
  int tid = threadIdx.x;
  for (int e = tid; e < T; e += 192) {
    float th = 6.283185307179586f * (float)e / (float)T;
    cs[e][0] = cosf(th);
    cs[e][1] = sinf(th);
  }
  int ch = cpair * 2 + (tid >= 96);
  int t = tid - ((tid >= 96) ? 96 : 0);
  const float* Rre = ws + Ro[s] + (size_t)x * 96 + t;
  const float* Rim = Rre + (size_t)T * 3072;
  __syncthreads();
  float zr = 0.f, zi = 0.f;
  if (s == 0)      s5_partial<6, 96>(Rre, Rim, cs, x, ch * 6, zr, zi);
  else if (s == 1) s5_partial<12, 192>(Rre, Rim, cs, x, ch * 12, zr, zi);
  else             s5_partial<24, 384>(Rre, Rim, cs, x, ch * 24, zr, zi);
  float* SCR = ws + SCROFF + (((size_t)(s * 32 + x) * 16 + ch) * 96 + t) * 2;
  SCR[0] = zr; SCR[1] = zi;
}

__global__ __launch_bounds__(192, 2) void k_s5f(const float* __restrict__ mlpw,
                                                float* __restrict__ ws) {
  int bid = blockIdx.x;
  int s = bid >> 8;
  int rem = bid & 255;
  int x = rem >> 3;
  int cpair = rem & 7;
  const int Ts[3] = {96, 192, 384};
  const int Ro[3] = {R0OFF, R1OFF, R2OFF};
  const int lpbase[3] = {288, 192, 0};
  int T = Ts[s];
  __shared__ float cs[384][2];
  int tid = threadIdx.x;
  for (int e = tid; e < T; e += 192) {
    float th = 6.283185307179586f * (float)e / (float)T;
    cs[e][0] = cosf(th);
    cs[e][1] = sinf(th);
  }
  int ch = cpair * 2 + (tid >= 96);
  int t = tid - ((tid >= 96) ? 96 : 0);
  const float* Rre = ws + Ro[s] + (size_t)x * 96 + t;
  const float* Rim = Rre + (size_t)T * 3072;
  // exclusive prefix of chunk partials < ch (L2-hot scratch, coalesced)
  const float* SCR = ws + SCROFF + ((size_t)(s * 32 + x) * 16 * 96 + t) * 2;
  float zr = 0.f, zi = 0.f;
  for (int cc = 0; cc < ch; ++cc) {
    zr += SCR[(size_t)cc * 192];
    zi += SCR[(size_t)cc * 192 + 1];
  }
  float wsc = mlpw[s];
  float sc = (((x == 0) ? 1.f : 2.f) / (float)T) * wsc;
  float* Hdst = ws + HTOTOFF + (size_t)lpbase[s] * 96;
  __syncthreads();
  if (s == 0)      s5_final<6, 96>(Rre, Rim, cs, x, ch * 6, zr, zi, sc, Hdst, t);
  else if (s == 1) s5_final<12, 192>(Rre, Rim, cs, x, ch * 12, zr, zi, sc, Hdst, t);
  else             s5_final<24, 384>(Rre, Rim, cs, x, ch * 24, zr, zi, sc, Hdst, t);
}

// ---- S6: out[b,t,j] = sum_l x*Htot + mean*(1-S[t]) + std*mlp_b ----
// Regridded 64 -> 192 blocks (each covers 8 t), LDS reads are broadcasts.
__global__ __launch_bounds__(256) void k_s6(const float* __restrict__ xin, const float* __restrict__ mlpb_p,
                                            const float* __restrict__ ws, float* __restrict__ out) {
  int b = blockIdx.x / 12, tc = blockIdx.x % 12;
  int tid = threadIdx.x;
  int j = tid & 63, tsub = tid >> 6;
  __shared__ float Ht[384 * 8];
  for (int idx = tid; idx < 384 * 8; idx += 256) {
    int lp = idx >> 3, c = idx & 7;
    Ht[idx] = ws[HTOTOFF + lp * 96 + tc * 8 + c];
  }
  float ssum = 0.f, sq = 0.f;
#pragma unroll
  for (int p = 0; p < 12; ++p) {
    const float* src = ws + STATSP + (((size_t)b * 12 + p) * 64 + j) * 2;
    ssum += src[0]; sq += src[1];
  }
  float mn = ssum * (1.f / 720.f);
  float var = sq * (1.f / 720.f) - mn * mn;
  float sd = sqrtf(var + 1e-5f);
  __syncthreads();
  float mlpb = mlpb_p[0];
  float acc0 = 0.f, acc1 = 0.f, accS0 = 0.f, accS1 = 0.f;
  const float* xp = xin + ((size_t)b * 720 + 336) * 64 + j;
  for (int lp = 0; lp < 384; ++lp) {
    float xv = xp[(size_t)lp * 64];
    float2 h = *(const float2*)&Ht[lp * 8 + tsub * 2];
    acc0 += xv * h.x; accS0 += h.x;
    acc1 += xv * h.y; accS1 += h.y;
  }
  int t = tc * 8 + tsub * 2;
  out[((size_t)b * 96 + t) * 64 + j] = acc0 + mn * (1.f - accS0) + sd * mlpb;
  out[((size_t)b * 96 + t + 1) * 64 + j] = acc1 + mn * (1.f - accS1) + sd * mlpb;
}

extern "C" void kernel_launch(void* const* d_in, const int* in_sizes, int n_in,
                              void* d_out, int out_size, void* d_ws, size_t ws_size,
                              hipStream_t stream) {
  const float* x  = (const float*)d_in[0];
  const float* wr = (const float*)d_in[1];
  const float* wi = (const float*)d_in[2];
  const float* mw = (const float*)d_in[3];
  const float* mb = (const float*)d_in[4];
  const float* Ab = (const float*)d_in[5];
  const float* Bb = (const float*)d_in[6];
  const float* ev = (const float*)d_in[7];
  float* wsf = (float*)d_ws;
  float* out = (float*)d_out;

  k_pre<<<1635, 256, 0, stream>>>(Ab, Bb, x, ev, wsf);

  const double* AD = (const double*)(wsf + WOFF) + AD64;
  double* PD = (double*)(wsf + WOFF) + PD64;
  double* KD = (double*)(wsf + WOFF) + KKD64;
  static const int Ts[3] = {96, 192, 384};
  static const int rowoff[3] = {0, 24576, 73728};

  // Doubling: round r extends KK rows [n, min(2n,T)) = KK[0,n) * P_n^T and
  // squares P_n -> P_2n (triple-buffered; free buf pre-zeroed for round r+1).
  int have[3] = {1, 1, 1};
  for (int r = 0; r <= 8; ++r) {
    CJobs jb;
    jb.njobs = 0;
    int tiles = 0;
    for (int s = 0; s < 3; ++s) {
      int T = Ts[s];
      if (have[s] >= T) continue;
      const double* Pn = (r == 0) ? (AD + (size_t)s * 65536)
                                  : (PD + (size_t)(s * 3 + (r - 1) % 3) * 65536);
      int M = ((2 * have[s] < T) ? 2 * have[s] : T) - have[s];
      int q = jb.njobs++;
      jb.A[q] = KD + rowoff[s]; jb.B[q] = Pn;
      jb.C[q] = KD + rowoff[s] + (size_t)have[s] * 256;
      jb.M[q] = M; jb.transB[q] = 1; jb.tile0[q] = tiles;
      tiles += ((M + 31) / 32) * 32;
      if (2 * have[s] < T) {
        q = jb.njobs++;
        jb.A[q] = Pn; jb.B[q] = Pn;
        jb.C[q] = PD + (size_t)(s * 3 + r % 3) * 65536;
        jb.M[q] = 256; jb.transB[q] = 0; jb.tile0[q] = tiles;
        tiles += 256;
        if (4 * have[s] < T) {  // will square next round: zero its dst now
          q = jb.njobs++;
          jb.A[q] = nullptr; jb.B[q] = nullptr;
          jb.C[q] = PD + (size_t)(s * 3 + (r + 1) % 3) * 65536;
          jb.M[q] = 0; jb.transB[q] = 2; jb.tile0[q] = tiles;
          tiles += 64;
        }
      }
      have[s] = (2 * have[s] < T) ? 2 * have[s] : T;
    }
    if (jb.njobs) k_chain<<<tiles, 256, 0, stream>>>(jb);
  }

  k_pack<<<672, 256, 0, stream>>>(wsf);
  k_s3<<<768, 384, 0, stream>>>(wr, wi, wsf);
  k_s4<<<504, 256, 0, stream>>>(wsf);
  k_s5p<<<768, 192, 0, stream>>>(wsf);
  k_s5f<<<768, 192, 0, stream>>>(mw, wsf);
  k_s6<<<192, 256, 0, stream>>>(x, mb, wsf, out);
}

// Round 8
// 305.091 us; speedup vs baseline: 1.2592x; 1.0382x over previous
//
#include <hip/hip_runtime.h>

typedef unsigned short u16;
typedef unsigned int u32;

typedef __bf16 bf16x8 __attribute__((ext_vector_type(8)));
typedef unsigned short ushort8 __attribute__((ext_vector_type(8)));
typedef float f32x16 __attribute__((ext_vector_type(16)));

// workspace offsets (in floats)
#define STATSP 2048     // 16*12*64*2 = 24576 floats of stats partials
#define EPOFF 32768     // E tables: Ehi[3][32][96][8] u16, then Elo same (73728 u16 each)
#define KKOFF0 591872   // per scale: KKhi[T*256] u16 then KKlo[T*256] u16, layout [i>>3][d][i&7]
#define KKOFF1 616448
#define KKOFF2 665600
#define WOFF 763904
#define R0OFF 5482496
#define R1OFF 6072320
#define R2OFF 7251968
#define SCROFF 9611264  // s5 chunk partials: [3][32][16][96][2] f32 = 294912 (free gap)
#define HTOTOFF 11675648
// total = 11712512 floats = ~46.9 MB
// fp64 chain scratch lives INSIDE the Wtil region [WOFF, R0OFF); it is fully
// consumed (k_pack) before k_s3 overwrites Wtil. Offsets in doubles relative
// to (double*)(ws + WOFF):
#define AD64 0        // 3*65536 doubles  (Ad fp64, per scale)
#define PD64 196608   // 9*65536 doubles  (P TRIPLE-buffer: (s*3+b)*65536)
#define KKD64 786432  // 672*256 doubles  (KK rows fp64: s0 96, s1 192, s2 384)
// Wtil2 (packed u32, layout [i>>3][n][i&7], n = x*96+t) at WOFF + jidx*786432 (u32).
// LAYOUT NOTE (R7 fix): E and KK fragment tables are stored BLOCKED-TRANSPOSED
// ([k>>3][row][k&7]) so MFMA fragment loads have 16B lane stride = 1KB
// contiguous per wave. The old [row][k] layout made every B-fragment load a
// 512B-lane-stride 64-sector gather -- that gather was the invariant ~42us
// latency wall across ALL five previous k_s3 structures (and k_s4's A side).

// float -> packed u32: low16 = bf16 RNE of a, high16 = bf16 of residual
__device__ __forceinline__ u32 pack_hl(float a) {
  u32 bits = __builtin_bit_cast(u32, a);
  u32 hi = (bits + 0x7fffu + ((bits >> 16) & 1u)) >> 16;
  float hif = __builtin_bit_cast(float, hi << 16);
  float r = a - hif;
  u32 lo = __builtin_bit_cast(u32, r) >> 16;
  return hi | (lo << 16);
}

__device__ __forceinline__ void unpk8(const u32* p, bf16x8& h, bf16x8& l) {
  ushort8 hu, lu;
#pragma unroll
  for (int j = 0; j < 8; ++j) {
    u32 v = p[j];
    hu[j] = (unsigned short)(v & 0xffffu);
    lu[j] = (unsigned short)(v >> 16);
  }
  h = __builtin_bit_cast(bf16x8, hu);
  l = __builtin_bit_cast(bf16x8, lu);
}

// async global->LDS, 16B per lane; LDS dest is wave-uniform base + lane*16
__device__ __forceinline__ void gload_lds16(const float* g, float* l) {
  __builtin_amdgcn_global_load_lds(
      (const __attribute__((address_space(1))) void*)g,
      (__attribute__((address_space(3))) void*)l, 16, 0, 0);
}

// ---- k_pre: A->fp64, seed KK row0, stats1, zero Htot/PD0/KD, pack E ----
__global__ __launch_bounds__(256) void k_pre(const float* __restrict__ Ab,
                                             const float* __restrict__ Bb,
                                             const float* __restrict__ xin,
                                             const float* __restrict__ ev,
                                             float* __restrict__ ws) {
  __shared__ float rs[4][64], rq[4][64];
  int blk = blockIdx.x, tid = threadIdx.x;
  if (blk < 771) {
    double* dws = (double*)(ws + WOFF);
    int idx = blk * 256 + tid;
    if (idx < 196608) {
      dws[AD64 + idx] = (double)Ab[idx];
    } else {
      int g = idx - 196608;  // 0..767 (grid sized exactly)
      const int rowoff[3] = {0, 24576, 73728};
      int s = g >> 8, i = g & 255;
      dws[KKD64 + rowoff[s] + i] = (double)Bb[g];
    }
  } else if (blk < 963) {
    int b2 = blk - 771;  // 0..191
    int b = b2 / 12, part = b2 % 12;
    int j = tid & 63, g = tid >> 6;
    const float* xp = xin + ((size_t)b * 720 + part * 60 + g) * 64 + j;
    float sum = 0.f, ss = 0.f;
#pragma unroll
    for (int i = 0; i < 15; ++i) {
      float v = xp[(size_t)i * 256];
      sum += v; ss += v * v;
    }
    rs[g][j] = sum; rq[g][j] = ss;
    __syncthreads();
    if (g == 0) {
      float s = rs[0][j] + rs[1][j] + rs[2][j] + rs[3][j];
      float q = rq[0][j] + rq[1][j] + rq[2][j] + rq[3][j];
      float* dst = ws + STATSP + ((size_t)b2 * 64 + j) * 2;
      dst[0] = s; dst[1] = q;
    }
  } else if (blk < 987) {
    int idx = (blk - 963) * 256 + tid;
    for (; idx < 36864; idx += 24 * 256) ws[HTOTOFF + idx] = 0.f;
  } else if (blk < 1275) {
    // E pack: ev [3][96][256] -> blocked-transposed u16 tables:
    // Ehi[s][o>>3][t][o&7] at eb[pos], Elo at eb[73728+pos]
    int idx = (blk - 987) * 256 + tid;  // 0..73727 (288 blocks exactly)
    int s = idx / 24576;
    int r = idx - s * 24576;
    int t = r >> 8, o = r & 255;
    u32 ph = pack_hl(ev[idx]);
    int pos = s * 24576 + (((o >> 3) * 96 + t) << 3) + (o & 7);
    u16* eb = (u16*)((u32*)ws + EPOFF);
    eb[pos] = (u16)(ph & 0xffffu);
    eb[73728 + pos] = (u16)(ph >> 16);
  } else if (blk < 1467) {
    // zero PD buf0 for each scale (dst of chain round 0)
    int g0 = ((blk - 1275) * 256 + tid) * 4;  // 0..196607, 192 blocks
    int s = g0 >> 16, off = g0 & 65535;
    double* dst = (double*)(ws + WOFF) + PD64 + (size_t)(s * 3) * 65536 + off;
    dst[0] = 0.; dst[1] = 0.; dst[2] = 0.; dst[3] = 0.;
  } else {
    // zero KD fp64 rows EXCEPT each scale's seeded row 0
    int g0 = ((blk - 1467) * 256 + tid) * 4;  // 0..172031, 168 blocks
    int local = (g0 < 24576) ? g0 : (g0 < 73728 ? g0 - 24576 : g0 - 73728);
    if (local >= 256) {
      double* dst = (double*)(ws + WOFF) + KKD64 + g0;
      dst[0] = 0.; dst[1] = 0.; dst[2] = 0.; dst[3] = 0.;
    }
  }
}

// ---- fp64 chain kernel: lean 32x32 tiles x 4-way K-split, atomic combine ----
struct CJobs {
  const double* A[12]; const double* B[12]; double* C[12];
  int M[12]; int transB[12]; int tile0[12];
  int njobs;
};

__global__ __launch_bounds__(256) void k_chain(CJobs jb) {
  int bid = blockIdx.x;
  int j = 0;
  for (int q = 1; q < jb.njobs; ++q) if (bid >= jb.tile0[q]) j = q;
  int local = bid - jb.tile0[j];
  int tB = jb.transB[j];
  int tid = threadIdx.x;
  if (tB == 2) {  // zero job: 64 tiles x 1024 doubles
    double* Z = jb.C[j] + (size_t)local * 1024 + tid * 4;
    Z[0] = 0.; Z[1] = 0.; Z[2] = 0.; Z[3] = 0.;
    return;
  }
  int M = jb.M[j];
  const double* A = jb.A[j];
  const double* Bm = jb.B[j];
  double* C = jb.C[j];
  int kq = local & 3, tn = (local >> 2) & 7, tm = local >> 5;
  int row0 = tm * 32, col0 = tn * 32, k0 = kq * 64;
  __shared__ double As[32][65];
  __shared__ double Bs[64][33];
  {
    int r = tid >> 3, k8 = (tid & 7) << 3;
    if (row0 + r < M) {
      const double* src = A + (size_t)(row0 + r) * 256 + k0 + k8;
#pragma unroll
      for (int u = 0; u < 8; ++u) As[r][k8 + u] = src[u];
    } else {
#pragma unroll
      for (int u = 0; u < 8; ++u) As[r][k8 + u] = 0.0;
    }
  }
  if (tB == 0) {
    int k = tid >> 2, c8 = (tid & 3) << 3;
    const double* src = Bm + (size_t)(k0 + k) * 256 + col0 + c8;
#pragma unroll
    for (int u = 0; u < 8; ++u) Bs[k][c8 + u] = src[u];
  } else {
    int c = tid >> 3, k8 = (tid & 7) << 3;
    const double* src = Bm + (size_t)(col0 + c) * 256 + k0 + k8;
#pragma unroll
    for (int u = 0; u < 8; ++u) Bs[k8 + u][c] = src[u];
  }
  __syncthreads();
  int ty = tid >> 4, tx = tid & 15;
  double a00 = 0., a01 = 0., a10 = 0., a11 = 0.;
#pragma unroll 8
  for (int k = 0; k < 64; ++k) {
    double x0 = As[2 * ty][k], x1 = As[2 * ty + 1][k];
    double y0 = Bs[k][2 * tx], y1 = Bs[k][2 * tx + 1];
    a00 = fma(x0, y0, a00); a01 = fma(x0, y1, a01);
    a10 = fma(x1, y0, a10); a11 = fma(x1, y1, a11);
  }
  int r0 = row0 + 2 * ty, c0 = col0 + 2 * tx;
  if (r0 < M) {
    __hip_atomic_fetch_add(&C[(size_t)r0 * 256 + c0], a00, __ATOMIC_RELAXED, __HIP_MEMORY_SCOPE_AGENT);
    __hip_atomic_fetch_add(&C[(size_t)r0 * 256 + c0 + 1], a01, __ATOMIC_RELAXED, __HIP_MEMORY_SCOPE_AGENT);
  }
  if (r0 + 1 < M) {
    __hip_atomic_fetch_add(&C[(size_t)(r0 + 1) * 256 + c0], a10, __ATOMIC_RELAXED, __HIP_MEMORY_SCOPE_AGENT);
    __hip_atomic_fetch_add(&C[(size_t)(r0 + 1) * 256 + c0 + 1], a11, __ATOMIC_RELAXED, __HIP_MEMORY_SCOPE_AGENT);
  }
}

// ---- k_pack: KK fp64 -> blocked-transposed hi/lo u16 tables ----
// KKhi[s][i>>3][d][i&7] at kb[pos], KKlo at kb[T*256+pos]
__global__ __launch_bounds__(256) void k_pack(float* __restrict__ ws) {
  int idx = blockIdx.x * 256 + threadIdx.x;  // 0..172031 (672 blocks)
  const double* KD = (const double*)(ws + WOFF) + KKD64;
  const int kko[3] = {KKOFF0, KKOFF1, KKOFF2};
  const int Ts[3] = {96, 192, 384};
  int s, local;
  if (idx < 24576) { s = 0; local = idx; }
  else if (idx < 73728) { s = 1; local = idx - 24576; }
  else { s = 2; local = idx - 73728; }
  int d = local >> 8, i = local & 255;
  int T = Ts[s];
  u32 ph = pack_hl((float)KD[idx]);
  int pos = (((i >> 3) * T + d) << 3) + (i & 7);
  u16* kb = (u16*)((u32*)ws + kko[s]);
  kb[pos] = (u16)(ph & 0xffffu);
  kb[T * 256 + pos] = (u16)(ph >> 16);
}

// ---- S3 (MFMA split-bf16, global_load_lds 2-phase, coalesced E): Wtil = w x E^T ----
__global__ __launch_bounds__(384, 5) void k_s3(const float* __restrict__ wr,
                                               const float* __restrict__ wi,
                                               float* __restrict__ ws) {
  __shared__ float stage[2][2048];   // 16 KB A staging
  __shared__ u32 pairs[3 * 1056];    // 12.7 KB epilogue pairing
  int bid = blockIdx.x;
  int jidx = bid >> 7;
  int r127 = bid & 127;
  int mb = ((r127 & 7) << 4) | (r127 >> 3);  // XCD-group swizzle (bijective)
  int s = jidx >> 1, p = jidx & 1;
  const float* w = (p ? wi : wr) + (size_t)s * 2097152;
  const u16* ebase = (const u16*)((const u32*)ws + EPOFF);
  int i0 = mb * 2;
  int tid = threadIdx.x;
  int lane = tid & 63;
  int wid = tid >> 6;
  int il = wid & 1, f = wid >> 1;

  int tcol = lane & 31;
  int og8 = (lane >> 5) << 3;
  // Blocked-transposed E: fragment = Ehi[s][g8][fr][0..8), g8 = c*4+ks*2+(lane>>5)
  // lane stride = 16B -> 1KB contiguous per wave (was 512B-stride gather).
  int fr = f * 32 + tcol;
  const u16* bhp = ebase + (size_t)s * 24576 + ((size_t)(lane >> 5) * 96 + fr) * 8;
  const u16* blp = bhp + 73728;

  bool stager = (wid < 4);
  int sq0 = wid * 2;
  int s_i[2], s_o[2], s_x[2];
#pragma unroll
  for (int j = 0; j < 2; ++j) {
    int qq = sq0 + j;
    s_i[j] = qq >> 2;
    s_o[j] = (qq & 3) * 8 + (lane >> 3);
    s_x[j] = (lane & 7) * 4;
  }

  f32x16 acc;
#pragma unroll
  for (int r = 0; r < 16; ++r) acc[r] = 0.f;

  if (stager) {
#pragma unroll
    for (int j = 0; j < 2; ++j) {
      const float* g = w + (((size_t)(i0 + s_i[j]) * 256 + s_o[j]) << 5) + s_x[j];
      gload_lds16(g, &stage[0][(sq0 + j) * 256]);
    }
  }
  __syncthreads();

#pragma unroll 2
  for (int c = 0; c < 8; ++c) {
    int buf = c & 1;
    if (c < 7 && stager) {
      int kon = (c + 1) * 32;
#pragma unroll
      for (int j = 0; j < 2; ++j) {
        const float* g = w + (((size_t)(i0 + s_i[j]) * 256 + kon + s_o[j]) << 5) + s_x[j];
        gload_lds16(g, &stage[buf ^ 1][(sq0 + j) * 256]);
      }
    }
#pragma unroll
    for (int ks = 0; ks < 2; ++ks) {
      int ob = ks * 16 + og8;
      float fa[8];
#pragma unroll
      for (int j = 0; j < 8; ++j)
        fa[j] = stage[buf][il * 1024 + (ob + j) * 32 + tcol];
      bf16x8 ah, al;
#pragma unroll
      for (int j = 0; j < 8; ++j) {
        __bf16 h = (__bf16)fa[j];
        ah[j] = h;
        al[j] = (__bf16)(fa[j] - (float)h);
      }
      int boff = (c * 4 + ks * 2) * 768;  // g8 step * 96 rows * 8
      bf16x8 bh = *(const bf16x8*)(bhp + boff);
      bf16x8 bl = *(const bf16x8*)(blp + boff);
      acc = __builtin_amdgcn_mfma_f32_32x32x16_bf16(ah, bh, acc, 0, 0, 0);
      acc = __builtin_amdgcn_mfma_f32_32x32x16_bf16(ah, bl, acc, 0, 0, 0);
      acc = __builtin_amdgcn_mfma_f32_32x32x16_bf16(al, bh, acc, 0, 0, 0);
    }
    __syncthreads();
  }

  // pack own values; pair il=0/il=1 through LDS; il=1 stores uint2
  int x0 = (lane >> 5) << 2;
  u32 mine[16];
#pragma unroll
  for (int r = 0; r < 16; ++r) mine[r] = pack_hl(acc[r]);
  if (il == 0) {
#pragma unroll
    for (int r = 0; r < 16; ++r) {
      int row = x0 + (r & 3) + ((r >> 2) << 3);
      pairs[f * 1056 + row * 33 + tcol] = mine[r];
    }
  }
  __syncthreads();
  if (il == 1) {
    u32* W2 = (u32*)(ws + WOFF) + (size_t)jidx * 786432 +
              (size_t)(mb >> 2) * 24576 + ((mb & 3) << 1);
#pragma unroll
    for (int r = 0; r < 16; ++r) {
      int row = x0 + (r & 3) + ((r >> 2) << 3);
      uint2 st;
      st.x = pairs[f * 1056 + row * 33 + tcol];
      st.y = mine[r];
      *(uint2*)(W2 + (size_t)(row * 96 + f * 32 + tcol) * 8) = st;
    }
  }
}

// ---- S4 (MFMA split-bf16, zero-LDS, coalesced A+B): R = KK x Wtil ----
__global__ __launch_bounds__(256) void k_s4(float* __restrict__ ws) {
  int bid = blockIdx.x;
  const int cums[6] = {0, 36, 72, 144, 216, 360};  // tiles: (T/32)*12 per (s,p)
  int jidx = 0;
#pragma unroll
  for (int q = 1; q < 6; ++q) if (bid >= cums[q]) jidx = q;
  int local = bid - cums[jidx];
  int s = jidx >> 1, p = jidx & 1;
  const int Ts[3] = {96, 192, 384};
  const int KKo[3] = {KKOFF0, KKOFF1, KKOFF2};
  const int Ro[3] = {R0OFF, R1OFF, R2OFF};
  int T = Ts[s];
  int td = local / 12, tn = local % 12;
  int d0 = td * 32;
  int tid = threadIdx.x;
  int lane = tid & 63, wid = tid >> 6;
  int n0 = tn * 256 + wid * 64;
  int l31 = lane & 31, kg = lane >> 5;
  // Blocked-transposed KK: fragment = KKhi[s][g8][d][0..8), g8 = ks*2+kg
  // lane stride (d) = 16B -> coalesced (was 1KB-stride gather).
  const u16* kb = (const u16*)((const u32*)ws + KKo[s]);
  const u16* ahp = kb + ((size_t)kg * T + d0 + l31) * 8;
  const u16* alp = ahp + (size_t)T * 256;
  const u32* Bp = (const u32*)ws + WOFF + (size_t)jidx * 786432 + (size_t)kg * 24576;
  const u32* b0p = Bp + (size_t)(n0 + l31) * 8;
  const u32* b1p = Bp + (size_t)(n0 + 32 + l31) * 8;
  float* C = ws + Ro[s] + (size_t)p * T * 3072;

  f32x16 acc0, acc1;
#pragma unroll
  for (int r = 0; r < 16; ++r) { acc0[r] = 0.f; acc1[r] = 0.f; }

#pragma unroll 2
  for (int ks = 0; ks < 16; ++ks) {
    bf16x8 ah = *(const bf16x8*)(ahp + (size_t)ks * T * 16);
    bf16x8 al = *(const bf16x8*)(alp + (size_t)ks * T * 16);
    size_t bo = (size_t)ks * 49152;
    uint4 x0 = *(const uint4*)(b0p + bo);
    uint4 x1 = *(const uint4*)(b0p + bo + 4);
    uint4 y0 = *(const uint4*)(b1p + bo);
    uint4 y1 = *(const uint4*)(b1p + bo + 4);
    {
      u32 bp[8] = {x0.x, x0.y, x0.z, x0.w, x1.x, x1.y, x1.z, x1.w};
      bf16x8 bh, bl;
      unpk8(bp, bh, bl);
      acc0 = __builtin_amdgcn_mfma_f32_32x32x16_bf16(ah, bh, acc0, 0, 0, 0);
      acc0 = __builtin_amdgcn_mfma_f32_32x32x16_bf16(ah, bl, acc0, 0, 0, 0);
      acc0 = __builtin_amdgcn_mfma_f32_32x32x16_bf16(al, bh, acc0, 0, 0, 0);
      acc0 = __builtin_amdgcn_mfma_f32_32x32x16_bf16(al, bl, acc0, 0, 0, 0);
    }
    {
      u32 bp[8] = {y0.x, y0.y, y0.z, y0.w, y1.x, y1.y, y1.z, y1.w};
      bf16x8 bh, bl;
      unpk8(bp, bh, bl);
      acc1 = __builtin_amdgcn_mfma_f32_32x32x16_bf16(ah, bh, acc1, 0, 0, 0);
      acc1 = __builtin_amdgcn_mfma_f32_32x32x16_bf16(ah, bl, acc1, 0, 0, 0);
      acc1 = __builtin_amdgcn_mfma_f32_32x32x16_bf16(al, bh, acc1, 0, 0, 0);
      acc1 = __builtin_amdgcn_mfma_f32_32x32x16_bf16(al, bl, acc1, 0, 0, 0);
    }
  }

  int crow = kg << 2;
#pragma unroll
  for (int r = 0; r < 16; ++r) {
    int row = d0 + crow + (r & 3) + ((r >> 2) << 3);
    C[(size_t)row * 3072 + n0 + l31] = acc0[r];
    C[(size_t)row * 3072 + n0 + 32 + l31] = acc1[r];
  }
}

// ---- S5 (two-phase decoupled prefix-DFT) ----
template <int LC, int T>
__device__ __forceinline__ void s5_partial(const float* __restrict__ Rre,
                                           const float* __restrict__ Rim,
                                           const float (*cs)[2], int x, int d0,
                                           float& zr, float& zi) {
#pragma unroll
  for (int u = 0; u < LC; ++u) {
    int d = d0 + u;
    float rr = Rre[(size_t)d * 3072];
    float ri = Rim[(size_t)d * 3072];
    int e1 = (x * d) % T;
    float c1 = cs[e1][0], s1 = cs[e1][1];
    zr += c1 * rr + s1 * ri;
    zi += c1 * ri - s1 * rr;
  }
}

template <int LC, int T>
__device__ __forceinline__ void s5_final(const float* __restrict__ Rre,
                                         const float* __restrict__ Rim,
                                         const float (*cs)[2], int x, int d0,
                                         float zr, float zi, float sc,
                                         float* __restrict__ Hdst, int t) {
#pragma unroll
  for (int u = 0; u < LC; ++u) {
    int d = d0 + u;
    float rr = Rre[(size_t)d * 3072];
    float ri = Rim[(size_t)d * 3072];
    int e1 = (x * d) % T;
    float c1 = cs[e1][0], s1 = cs[e1][1];
    zr += c1 * rr + s1 * ri;
    zi += c1 * ri - s1 * rr;
    int k = T - 1 - d;
    int e2 = (x * (95 - k)) % T;
    if (e2 < 0) e2 += T;
    float c2 = cs[e2][0], s2 = cs[e2][1];
    atomicAdd(Hdst + (size_t)k * 96 + t, sc * (c2 * zr - s2 * zi));
  }
}

__global__ __launch_bounds__(192, 2) void k_s5p(float* __restrict__ ws) {
  int bid = blockIdx.x;                 // 768 = 3 s x 32 x x 8 cpair
  int s = bid >> 8;
  int rem = bid & 255;
  int x = rem >> 3;
  int cpair = rem & 7;
  const int Ts[3] = {96, 192, 384};
  const int Ro[3] = {R0OFF, R1OFF, R2OFF};
  int T = Ts[s];
  __shared__ float cs[384][2];
  int tid = threadIdx.x;
  for (int e = tid; e < T; e += 192) {
    float th = 6.283185307179586f * (float)e / (float)T;
    cs[e][0] = cosf(th);
    cs[e][1] = sinf(th);
  }
  int ch = cpair * 2 + (tid >= 96);
  int t = tid - ((tid >= 96) ? 96 : 0);
  const float* Rre = ws + Ro[s] + (size_t)x * 96 + t;
  const float* Rim = Rre + (size_t)T * 3072;
  __syncthreads();
  float zr = 0.f, zi = 0.f;
  if (s == 0)      s5_partial<6, 96>(Rre, Rim, cs, x, ch * 6, zr, zi);
  else if (s == 1) s5_partial<12, 192>(Rre, Rim, cs, x, ch * 12, zr, zi);
  else             s5_partial<24, 384>(Rre, Rim, cs, x, ch * 24, zr, zi);
  float* SCR = ws + SCROFF + (((size_t)(s * 32 + x) * 16 + ch) * 96 + t) * 2;
  SCR[0] = zr; SCR[1] = zi;
}

__global__ __launch_bounds__(192, 2) void k_s5f(const float* __restrict__ mlpw,
                                                float* __restrict__ ws) {
  int bid = blockIdx.x;
  int s = bid >> 8;
  int rem = bid & 255;
  int x = rem >> 3;
  int cpair = rem & 7;
  const int Ts[3] = {96, 192, 384};
  const int Ro[3] = {R0OFF, R1OFF, R2OFF};
  const int lpbase[3] = {288, 192, 0};
  int T = Ts[s];
  __shared__ float cs[384][2];
  int tid = threadIdx.x;
  for (int e = tid; e < T; e += 192) {
    float th = 6.283185307179586f * (float)e / (float)T;
    cs[e][0] = cosf(th);
    cs[e][1] = sinf(th);
  }
  int ch = cpair * 2 + (tid >= 96);
  int t = tid - ((tid >= 96) ? 96 : 0);
  const float* Rre = ws + Ro[s] + (size_t)x * 96 + t;
  const float* Rim = Rre + (size_t)T * 3072;
  const float* SCR = ws + SCROFF + ((size_t)(s * 32 + x) * 16 * 96 + t) * 2;
  float zr = 0.f, zi = 0.f;
  for (int cc = 0; cc < ch; ++cc) {
    zr += SCR[(size_t)cc * 192];
    zi += SCR[(size_t)cc * 192 + 1];
  }
  float wsc = mlpw[s];
  float sc = (((x == 0) ? 1.f : 2.f) / (float)T) * wsc;
  float* Hdst = ws + HTOTOFF + (size_t)lpbase[s] * 96;
  __syncthreads();
  if (s == 0)      s5_final<6, 96>(Rre, Rim, cs, x, ch * 6, zr, zi, sc, Hdst, t);
  else if (s == 1) s5_final<12, 192>(Rre, Rim, cs, x, ch * 12, zr, zi, sc, Hdst, t);
  else             s5_final<24, 384>(Rre, Rim, cs, x, ch * 24, zr, zi, sc, Hdst, t);
}

// ---- S6: out[b,t,j] = sum_l x*Htot + mean*(1-S[t]) + std*mlp_b ----
__global__ __launch_bounds__(256) void k_s6(const float* __restrict__ xin, const float* __restrict__ mlpb_p,
                                            const float* __restrict__ ws, float* __restrict__ out) {
  int b = blockIdx.x / 12, tc = blockIdx.x % 12;
  int tid = threadIdx.x;
  int j = tid & 63, tsub = tid >> 6;
  __shared__ float Ht[384 * 8];
  for (int idx = tid; idx < 384 * 8; idx += 256) {
    int lp = idx >> 3, c = idx & 7;
    Ht[idx] = ws[HTOTOFF + lp * 96 + tc * 8 + c];
  }
  float ssum = 0.f, sq = 0.f;
#pragma unroll
  for (int p = 0; p < 12; ++p) {
    const float* src = ws + STATSP + (((size_t)b * 12 + p) * 64 + j) * 2;
    ssum += src[0]; sq += src[1];
  }
  float mn = ssum * (1.f / 720.f);
  float var = sq * (1.f / 720.f) - mn * mn;
  float sd = sqrtf(var + 1e-5f);
  __syncthreads();
  float mlpb = mlpb_p[0];
  float acc0 = 0.f, acc1 = 0.f, accS0 = 0.f, accS1 = 0.f;
  const float* xp = xin + ((size_t)b * 720 + 336) * 64 + j;
  for (int lp = 0; lp < 384; ++lp) {
    float xv = xp[(size_t)lp * 64];
    float2 h = *(const float2*)&Ht[lp * 8 + tsub * 2];
    acc0 += xv * h.x; accS0 += h.x;
    acc1 += xv * h.y; accS1 += h.y;
  }
  int t = tc * 8 + tsub * 2;
  out[((size_t)b * 96 + t) * 64 + j] = acc0 + mn * (1.f - accS0) + sd * mlpb;
  out[((size_t)b * 96 + t + 1) * 64 + j] = acc1 + mn * (1.f - accS1) + sd * mlpb;
}

extern "C" void kernel_launch(void* const* d_in, const int* in_sizes, int n_in,
                              void* d_out, int out_size, void* d_ws, size_t ws_size,
                              hipStream_t stream) {
  const float* x  = (const float*)d_in[0];
  const float* wr = (const float*)d_in[1];
  const float* wi = (const float*)d_in[2];
  const float* mw = (const float*)d_in[3];
  const float* mb = (const float*)d_in[4];
  const float* Ab = (const float*)d_in[5];
  const float* Bb = (const float*)d_in[6];
  const float* ev = (const float*)d_in[7];
  float* wsf = (float*)d_ws;
  float* out = (float*)d_out;

  k_pre<<<1635, 256, 0, stream>>>(Ab, Bb, x, ev, wsf);

  const double* AD = (const double*)(wsf + WOFF) + AD64;
  double* PD = (double*)(wsf + WOFF) + PD64;
  double* KD = (double*)(wsf + WOFF) + KKD64;
  static const int Ts[3] = {96, 192, 384};
  static const int rowoff[3] = {0, 24576, 73728};

  // Doubling: round r extends KK rows [n, min(2n,T)) = KK[0,n) * P_n^T and
  // squares P_n -> P_2n (triple-buffered; free buf pre-zeroed for round r+1).
  int have[3] = {1, 1, 1};
  for (int r = 0; r <= 8; ++r) {
    CJobs jb;
    jb.njobs = 0;
    int tiles = 0;
    for (int s = 0; s < 3; ++s) {
      int T = Ts[s];
      if (have[s] >= T) continue;
      const double* Pn = (r == 0) ? (AD + (size_t)s * 65536)
                                  : (PD + (size_t)(s * 3 + (r - 1) % 3) * 65536);
      int M = ((2 * have[s] < T) ? 2 * have[s] : T) - have[s];
      int q = jb.njobs++;
      jb.A[q] = KD + rowoff[s]; jb.B[q] = Pn;
      jb.C[q] = KD + rowoff[s] + (size_t)have[s] * 256;
      jb.M[q] = M; jb.transB[q] = 1; jb.tile0[q] = tiles;
      tiles += ((M + 31) / 32) * 32;
      if (2 * have[s] < T) {
        q = jb.njobs++;
        jb.A[q] = Pn; jb.B[q] = Pn;
        jb.C[q] = PD + (size_t)(s * 3 + r % 3) * 65536;
        jb.M[q] = 256; jb.transB[q] = 0; jb.tile0[q] = tiles;
        tiles += 256;
        if (4 * have[s] < T) {  // will square next round: zero its dst now
          q = jb.njobs++;
          jb.A[q] = nullptr; jb.B[q] = nullptr;
          jb.C[q] = PD + (size_t)(s * 3 + (r + 1) % 3) * 65536;
          jb.M[q] = 0; jb.transB[q] = 2; jb.tile0[q] = tiles;
          tiles += 64;
        }
      }
      have[s] = (2 * have[s] < T) ? 2 * have[s] : T;
    }
    if (jb.njobs) k_chain<<<tiles, 256, 0, stream>>>(jb);
  }

  k_pack<<<672, 256, 0, stream>>>(wsf);
  k_s3<<<768, 384, 0, stream>>>(wr, wi, wsf);
  k_s4<<<504, 256, 0, stream>>>(wsf);
  k_s5p<<<768, 192, 0, stream>>>(wsf);
  k_s5f<<<768, 192, 0, stream>>>(mw, wsf);
  k_s6<<<192, 256, 0, stream>>>(x, mb, wsf, out);
}